// Round 15
// baseline (583.813 us; speedup 1.0000x reference)
//
#include <hip/hip_runtime.h>
#include <math.h>

static constexpr int T = 4096;   // B*S
static constexpr int D = 1024;

typedef __bf16 bf16_t;
typedef bf16_t bf16x8 __attribute__((ext_vector_type(8)));
typedef bf16_t bf16x4 __attribute__((ext_vector_type(4)));
typedef float f32x4 __attribute__((ext_vector_type(4)));

#define GLDS16(g, l)                                                        \
  __builtin_amdgcn_global_load_lds(                                         \
      (const __attribute__((address_space(1))) void*)(g),                   \
      (__attribute__((address_space(3))) void*)(l), 16, 0, 0)

// ======================= small kernels =======================

__global__ void zero1_kernel(float* p) { *p = 0.f; }

__global__ __launch_bounds__(256) void ln_kernel(
    const float* __restrict__ x, const float* __restrict__ scale,
    const float* __restrict__ bias, float* __restrict__ out_f,
    bf16_t* __restrict__ out_b)
{
  int t = blockIdx.x;
  const float* xr = x + (size_t)t * D;
  float v[4];
  float s1 = 0.f, s2 = 0.f;
#pragma unroll
  for (int i = 0; i < 4; i++) {
    v[i] = xr[threadIdx.x + i * 256];
    s1 += v[i];
    s2 += v[i] * v[i];
  }
#pragma unroll
  for (int o = 1; o < 64; o <<= 1) {
    s1 += __shfl_xor(s1, o);
    s2 += __shfl_xor(s2, o);
  }
  __shared__ float r1[4], r2[4];
  int wid = threadIdx.x >> 6;
  if ((threadIdx.x & 63) == 0) { r1[wid] = s1; r2[wid] = s2; }
  __syncthreads();
  s1 = r1[0] + r1[1] + r1[2] + r1[3];
  s2 = r2[0] + r2[1] + r2[2] + r2[3];
  float mean = s1 * (1.f / D);
  float var = s2 * (1.f / D) - mean * mean;
  float rstd = rsqrtf(var + 1e-6f);
  float* orow = out_f + (size_t)t * D;
  bf16_t* brow = out_b + (size_t)t * D;
#pragma unroll
  for (int i = 0; i < 4; i++) {
    int d = threadIdx.x + i * 256;
    float o = (v[i] - mean) * rstd * scale[d] + bias[d];
    orow[d] = o;
    brow[d] = (bf16_t)o;
  }
}

// rows of length 128, one wave per row; bf16 normalized output
__global__ __launch_bounds__(64) void norm_rows_kernel(
    const float* __restrict__ e, bf16_t* __restrict__ o)
{
  int r = blockIdx.x;
  const float* row = e + (size_t)r * 128;
  float a = row[threadIdx.x], b = row[threadIdx.x + 64];
  float ss = a * a + b * b;
#pragma unroll
  for (int m = 1; m < 64; m <<= 1) ss += __shfl_xor(ss, m);
  float inv = 1.f / (sqrtf(ss) + 1e-8f);
  bf16_t* orow = o + (size_t)r * 128;
  orow[threadIdx.x] = (bf16_t)(a * inv);
  orow[threadIdx.x + 64] = (bf16_t)(b * inv);
}

// tau = n @ W + b,  W: [D, J], J in {1,3}; one wave per token (fp32)
__global__ __launch_bounds__(64) void tau_kernel(
    const float* __restrict__ n, const float* __restrict__ W,
    const float* __restrict__ b, float* __restrict__ out, int J)
{
  int t = blockIdx.x;
  const float* nr = n + (size_t)t * D;
  for (int j = 0; j < J; j++) {
    float p = 0.f;
#pragma unroll 4
    for (int i = 0; i < 16; i++) {
      int d = threadIdx.x + i * 64;
      p += nr[d] * W[d * J + j];
    }
#pragma unroll
    for (int m = 1; m < 64; m <<= 1) p += __shfl_xor(p, m);
    if (threadIdx.x == 0) out[t * J + j] = p + b[j];
  }
}

// ======== gate (bf16 scores, no write-back; emits gb + rowinv) ========
template <int PER>
__device__ __forceinline__ void gateb_body(
    const bf16_t* __restrict__ row, float tv, float* __restrict__ gb, int G,
    float* __restrict__ rowinv)
{
  int base = threadIdx.x * PER;
  float psum = 0.f;
#pragma unroll
  for (int i = 0; i < PER; i += 8) {
    bf16x8 v = *(const bf16x8*)(row + base + i);
#pragma unroll
    for (int j = 0; j < 8; j++) psum += fmaxf((float)v[j] - tv, 0.f);
  }
  __shared__ float red[4];
  __shared__ float grp[32];
  if (threadIdx.x < 32) grp[threadIdx.x] = 0.f;
  float w = psum;
#pragma unroll
  for (int m = 1; m < 64; m <<= 1) w += __shfl_xor(w, m);
  int wid = threadIdx.x >> 6;
  if ((threadIdx.x & 63) == 0) red[wid] = w;
  __syncthreads();
  float Stot = red[0] + red[1] + red[2] + red[3];
  atomicAdd(&grp[base >> 7], psum);
  __syncthreads();
  float inv = 1.f / (Stot + 1e-8f);
  if (threadIdx.x == 0) *rowinv = inv;
  if (threadIdx.x < G) {
    float Gj = grp[threadIdx.x] * inv;
    float gsum = Stot * inv;
    gb[threadIdx.x] = Gj / (gsum + 1e-8f);
  }
}

template <int PER>
__global__ __launch_bounds__(256) void gate3b_kernel(
    const bf16_t* __restrict__ s0, const bf16_t* __restrict__ s1,
    const bf16_t* __restrict__ s2, const float* __restrict__ tau,
    float* __restrict__ g0, float* __restrict__ g1, float* __restrict__ g2,
    float* __restrict__ ri, int N, int G)
{
  int t = blockIdx.x, y = blockIdx.y;
  const bf16_t* g = y == 0 ? s0 : y == 1 ? s1 : s2;
  float* gb = y == 0 ? g0 : y == 1 ? g1 : g2;
  gateb_body<PER>(g + (size_t)t * N, tau[t * 3 + y], gb + (size_t)t * G, G,
                  ri + (size_t)y * T + t);
}

template <int PER>
__global__ __launch_bounds__(256) void gateb_kernel(
    const bf16_t* __restrict__ s, const float* __restrict__ tau,
    float* __restrict__ gb, float* __restrict__ ri, int N, int G)
{
  int t = blockIdx.x;
  gateb_body<PER>(s + (size_t)t * N, tau[t], gb + (size_t)t * G, G, ri + t);
}

// column partial sums of normalized gates, recomputed from bf16 scores
__global__ __launch_bounds__(256) void colsumb_part3_kernel(
    const bf16_t* __restrict__ s0, const bf16_t* __restrict__ s1,
    const bf16_t* __restrict__ s2, const float* __restrict__ tau,
    const float* __restrict__ ri, int N, float* __restrict__ colsum)
{
  int z = blockIdx.z;
  const bf16_t* g = z == 0 ? s0 : z == 1 ? s1 : s2;
  const float* riz = ri + (size_t)z * T;
  int c = blockIdx.x * 256 + threadIdx.x;
  int r0 = blockIdx.y * 128;
  float s = 0.f;
#pragma unroll 4
  for (int t = 0; t < 128; t++) {
    int row = r0 + t;
    float v = (float)g[(size_t)row * N + c];
    s += fmaxf(v - tau[row * 3 + z], 0.f) * riz[row];
  }
  atomicAdd(&colsum[z * N + c], s);
}

__global__ __launch_bounds__(256) void colsumb_part_kernel(
    const bf16_t* __restrict__ g, const float* __restrict__ tau,
    const float* __restrict__ ri, int N, float* __restrict__ colsum)
{
  int c = blockIdx.x * 256 + threadIdx.x;
  int r0 = blockIdx.y * 128;
  float s = 0.f;
#pragma unroll 4
  for (int t = 0; t < 128; t++) {
    int row = r0 + t;
    float v = (float)g[(size_t)row * N + c];
    s += fmaxf(v - tau[row], 0.f) * ri[row];
  }
  atomicAdd(&colsum[c], s);
}

// stage 2: aux += sum_c (colsum[c]/T - tinv)^2 * N
__global__ __launch_bounds__(256) void colsum_fin_kernel(
    const float* __restrict__ colsum, int N, float tinv,
    float* __restrict__ aux)
{
  int c = blockIdx.x * 256 + threadIdx.x;
  float mdev = colsum[c] * (1.f / T) - tinv;
  float p = mdev * mdev * (float)N;
#pragma unroll
  for (int m = 1; m < 64; m <<= 1) p += __shfl_xor(p, m);
  __shared__ float red[4];
  if ((threadIdx.x & 63) == 0) red[threadIdx.x >> 6] = p;
  __syncthreads();
  if (threadIdx.x == 0) atomicAdd(aux, red[0] + red[1] + red[2] + red[3]);
}

// h1[t,r] = sum_n gb1[t,n]*all_h[t, n*128+r] (all_h bf16); optional 2nd out
__global__ __launch_bounds__(128) void wsum2_kernel(
    const bf16_t* __restrict__ all_h, const float* __restrict__ gb1,
    const float* __restrict__ gb2, float* __restrict__ h1,
    float* __restrict__ h2, int NB)
{
  int t = blockIdx.x;
  int r = threadIdx.x;
  const bf16_t* row = all_h + (size_t)t * NB * 128;
  float a1 = 0.f, a2 = 0.f;
  for (int n = 0; n < NB; n++) {
    float v = (float)row[n * 128 + r];
    a1 += gb1[(size_t)t * NB + n] * v;
    if (gb2) a2 += gb2[(size_t)t * NB + n] * v;
  }
  h1[(size_t)t * 128 + r] = a1;
  if (h2) h2[(size_t)t * 128 + r] = a2;
}

__global__ __launch_bounds__(128) void wsum2b_kernel(
    const bf16_t* __restrict__ aq, const bf16_t* __restrict__ av,
    const float* __restrict__ gq, const float* __restrict__ gk,
    const float* __restrict__ gv, float* __restrict__ hQ,
    float* __restrict__ hK, float* __restrict__ hV, int NB)
{
  int t = blockIdx.x, y = blockIdx.y;
  int r = threadIdx.x;
  const bf16_t* row = (y == 0 ? aq : av) + (size_t)t * NB * 128;
  const float* g1 = (y == 0 ? gq : gv) + (size_t)t * NB;
  const float* g2 = y == 0 ? gk + (size_t)t * NB : nullptr;
  float a1 = 0.f, a2 = 0.f;
  for (int n = 0; n < NB; n++) {
    float v = (float)row[n * 128 + r];
    a1 += g1[n] * v;
    if (g2) a2 += g2[n] * v;
  }
  if (y == 0) {
    hQ[(size_t)t * 128 + r] = a1;
    hK[(size_t)t * 128 + r] = a2;
  } else {
    hV[(size_t)t * 128 + r] = a1;
  }
}

// dst[c][r] = (bf16)src[r][c]; src [R,C] fp32, dst [C,R] bf16; batched
__global__ __launch_bounds__(256) void transpose_to_bf16_kernel(
    const float* __restrict__ src, bf16_t* __restrict__ dst,
    int R, int C, size_t sbs, size_t dbs)
{
  __shared__ float tile[32][33];
  int b = blockIdx.z;
  int c0 = blockIdx.x * 32, r0 = blockIdx.y * 32;
  int tx = threadIdx.x & 31, ty = threadIdx.x >> 5;
  const float* s = src + (size_t)b * sbs;
  bf16_t* d = dst + (size_t)b * dbs;
#pragma unroll
  for (int i = 0; i < 4; i++)
    tile[ty + i * 8][tx] = s[(size_t)(r0 + ty + i * 8) * C + c0 + tx];
  __syncthreads();
#pragma unroll
  for (int i = 0; i < 4; i++)
    d[(size_t)(c0 + ty + i * 8) * R + r0 + tx] = (bf16_t)tile[tx][ty + i * 8];
}

// A_virt[t,k] = (bf16)(gb[t,k>>7]*h[t,k&127]), row-major [T,K]
__device__ __forceinline__ void avirt_body(
    const float* hr, const float* gr, bf16_t* ar, int K)
{
  int noct = K >> 3;
  for (int o = threadIdx.x; o < noct; o += 256) {
    int k = o * 8;
    float g = gr[k >> 7];
    bf16x8 v;
#pragma unroll
    for (int i = 0; i < 8; i++) v[i] = (bf16_t)(hr[(k & 127) + i] * g);
    *(bf16x8*)(ar + k) = v;
  }
}

__global__ __launch_bounds__(256) void avirt_kernel(
    const float* __restrict__ h, const float* __restrict__ gb, int NB,
    bf16_t* __restrict__ A, int K)
{
  int t = blockIdx.x;
  avirt_body(h + (size_t)t * 128, gb + (size_t)t * NB, A + (size_t)t * K, K);
}

__global__ __launch_bounds__(256) void avirt3_kernel(
    const float* __restrict__ h0, const float* __restrict__ h1,
    const float* __restrict__ h2, const float* __restrict__ g0,
    const float* __restrict__ g1, const float* __restrict__ g2, int NB,
    bf16_t* __restrict__ A0, bf16_t* __restrict__ A1,
    bf16_t* __restrict__ A2, int K)
{
  int t = blockIdx.x, y = blockIdx.y;
  const float* h = y == 0 ? h0 : y == 1 ? h1 : h2;
  const float* g = y == 0 ? g0 : y == 1 ? g1 : g2;
  bf16_t* A = y == 0 ? A0 : y == 1 ? A1 : A2;
  avirt_body(h + (size_t)t * 128, g + (size_t)t * NB, A + (size_t)t * K, K);
}

// out[i] += p0[i] + p1[i]
__global__ __launch_bounds__(256) void combine2_kernel(
    const float* __restrict__ p0, const float* __restrict__ p1,
    float* __restrict__ out)
{
  int i = blockIdx.x * 256 + threadIdx.x;
  float4 a = ((const float4*)p0)[i];
  float4 b = ((const float4*)p1)[i];
  float4 o = ((float4*)out)[i];
  o.x += a.x + b.x;
  o.y += a.y + b.y;
  o.z += a.z + b.z;
  o.w += a.w + b.w;
  ((float4*)out)[i] = o;
}

// ======== epilogue helper (shared by all GEMM variants) ========
template <bool HAS_BIAS, bool HAS_RESID>
__device__ __forceinline__ void gemm_store(
    int mode, void* Cv, int ldc, const float* bias, const float* resid,
    int ldr, int rowb, int col, const f32x4& a)
{
  if (mode == 2) {
    bf16x4 v4;
#pragma unroll
    for (int r = 0; r < 4; r++) v4[r] = (bf16_t)a[r];
    bf16_t* dst = (bf16_t*)Cv +
        ((size_t)(rowb >> 10) * 1024 + col) * 1024 + (rowb & 1023);
    *(bf16x4*)dst = v4;
  } else {
#pragma unroll
    for (int r = 0; r < 4; r++) {
      int row = rowb + r;
      float v = a[r];
      if (HAS_BIAS) v += bias[col];
      if (HAS_RESID) v += resid[(size_t)row * ldr + col];
      if (mode == 1)
        ((bf16_t*)Cv)[(size_t)row * ldc + col] = (bf16_t)v;
      else
        ((float*)Cv)[(size_t)row * ldc + col] = v;
    }
  }
}

// ============== MFMA GEMM (64x128 tile) — narrow-N dispatches ==============
template <bool HAS_BIAS, bool HAS_RESID, int OUT_MODE>
__global__ __launch_bounds__(256) void mfma_gemm_kernel(
    const bf16_t* __restrict__ A, int lda,
    const bf16_t* __restrict__ Bt, int ldb,
    void* __restrict__ Cv, int ldc,
    const float* __restrict__ bias,
    const float* __restrict__ resid, int ldr,
    int M, int N, int K)
{
  __shared__ bf16_t As[2][64 * 32];
  __shared__ bf16_t Bs[2][128 * 32];
  int tid = threadIdx.x;
  int wave = tid >> 6, lane = tid & 63;

  unsigned lid = blockIdx.y * gridDim.x + blockIdx.x;
  unsigned nwg = gridDim.x * gridDim.y;
  unsigned swzb = lid;
  if ((nwg & 7u) == 0u) swzb = (lid & 7u) * (nwg >> 3) + (lid >> 3);
  int row0 = (int)(swzb / gridDim.x) * 64;
  int col0 = (int)(swzb % gridDim.x) * 128;

  int wr = (wave >> 1) * 32, wc = (wave & 1) * 64;
  f32x4 acc[2][4] = {};

  int srow = (wave << 4) + (lane >> 2);
  int g8 = (((lane & 3) ^ ((srow >> 1) & 3)) << 3);
  const bf16_t* gA = A + (size_t)(row0 + srow) * lda + g8;
  const bf16_t* gB = Bt + (size_t)(col0 + srow) * ldb + g8;
  size_t b64 = (size_t)64 * ldb;

  int fr = lane & 15, fq = lane >> 4;

#define GSTAGE(buf, k0s)                                  \
  {                                                       \
    GLDS16(gA + (k0s), &As[buf][wave * 512]);             \
    GLDS16(gB + (k0s), &Bs[buf][wave * 512]);             \
    GLDS16(gB + b64 + (k0s), &Bs[buf][2048 + wave * 512]);\
  }

  GSTAGE(0, 0);
  int cur = 0;
  for (int k0 = 0; k0 < K; k0 += 32) {
    __syncthreads();
    if (k0 + 32 < K) GSTAGE(cur ^ 1, k0 + 32);
    bf16x8 af[2], bfr[4];
#pragma unroll
    for (int m = 0; m < 2; m++) {
      int R = wr + m * 16 + fr;
      af[m] = *(const bf16x8*)&As[cur][R * 32 + ((fq ^ ((R >> 1) & 3)) << 3)];
    }
#pragma unroll
    for (int n = 0; n < 4; n++) {
      int R = wc + n * 16 + fr;
      bfr[n] = *(const bf16x8*)&Bs[cur][R * 32 + ((fq ^ ((R >> 1) & 3)) << 3)];
    }
#pragma unroll
    for (int m = 0; m < 2; m++)
#pragma unroll
      for (int n = 0; n < 4; n++)
        acc[m][n] = __builtin_amdgcn_mfma_f32_16x16x32_bf16(af[m], bfr[n],
                                                            acc[m][n], 0, 0, 0);
    cur ^= 1;
  }
#undef GSTAGE

#pragma unroll
  for (int m = 0; m < 2; m++)
#pragma unroll
    for (int n = 0; n < 4; n++)
      gemm_store<HAS_BIAS, HAS_RESID>(
          OUT_MODE, Cv, ldc, bias, resid, ldr,
          row0 + wr + m * 16 + fq * 4, col0 + wc + n * 16 + fr, acc[m][n]);
}

// ============== MFMA GEMM (128x128 tile) — wide dispatches ==============
// Per-z heterogeneous {A, lda, Bt, ldb, C, mode, K}.
struct ZArg { const bf16_t* A; int lda; const bf16_t* Bt; int ldb;
              void* C; int mode; int K; };

__device__ __forceinline__ void gemm128_body(
    const bf16_t* __restrict__ A, int lda, const bf16_t* __restrict__ Bt,
    int ldb, void* __restrict__ Cv, int ldc, int mode, int row0, int col0,
    int K)
{
  __shared__ bf16_t As[2][128 * 32];
  __shared__ bf16_t Bs[2][128 * 32];
  int tid = threadIdx.x;
  int wave = tid >> 6, lane = tid & 63;
  int wr = (wave >> 1) * 64, wc = (wave & 1) * 64;
  f32x4 acc[4][4] = {};

  int srow = (wave << 4) + (lane >> 2);
  int g8 = (((lane & 3) ^ ((srow >> 1) & 3)) << 3);
  const bf16_t* gA = A + (size_t)(row0 + srow) * lda + g8;
  const bf16_t* gB = Bt + (size_t)(col0 + srow) * ldb + g8;
  size_t a64 = (size_t)64 * lda, b64 = (size_t)64 * ldb;

  int fr = lane & 15, fq = lane >> 4;

#define GSTAGE8(buf, k0s)                                  \
  {                                                        \
    GLDS16(gA + (k0s), &As[buf][wave * 512]);              \
    GLDS16(gA + a64 + (k0s), &As[buf][2048 + wave * 512]); \
    GLDS16(gB + (k0s), &Bs[buf][wave * 512]);              \
    GLDS16(gB + b64 + (k0s), &Bs[buf][2048 + wave * 512]); \
  }

  GSTAGE8(0, 0);
  int cur = 0;
  for (int k0 = 0; k0 < K; k0 += 32) {
    __syncthreads();
    if (k0 + 32 < K) GSTAGE8(cur ^ 1, k0 + 32);
    bf16x8 af[4], bfr[4];
#pragma unroll
    for (int m = 0; m < 4; m++) {
      int R = wr + m * 16 + fr;
      af[m] = *(const bf16x8*)&As[cur][R * 32 + ((fq ^ ((R >> 1) & 3)) << 3)];
    }
#pragma unroll
    for (int n = 0; n < 4; n++) {
      int R = wc + n * 16 + fr;
      bfr[n] = *(const bf16x8*)&Bs[cur][R * 32 + ((fq ^ ((R >> 1) & 3)) << 3)];
    }
#pragma unroll
    for (int m = 0; m < 4; m++)
#pragma unroll
      for (int n = 0; n < 4; n++)
        acc[m][n] = __builtin_amdgcn_mfma_f32_16x16x32_bf16(af[m], bfr[n],
                                                            acc[m][n], 0, 0, 0);
    cur ^= 1;
  }
#undef GSTAGE8

#pragma unroll
  for (int m = 0; m < 4; m++)
#pragma unroll
    for (int n = 0; n < 4; n++)
      gemm_store<false, false>(
          mode, Cv, ldc, nullptr, nullptr, 0,
          row0 + wr + m * 16 + fq * 4, col0 + wc + n * 16 + fr, acc[m][n]);
}

__global__ __launch_bounds__(256) void mfma_gemm128b_kernel(
    ZArg za, ZArg zb, ZArg zc, int ldc)
{
  unsigned gx = gridDim.x;
  unsigned gxy = gridDim.x * gridDim.y;
  unsigned lid = (blockIdx.z * gridDim.y + blockIdx.y) * gx + blockIdx.x;
  unsigned nwg = gxy * gridDim.z;
  unsigned swzb = lid;
  if ((nwg & 7u) == 0u) swzb = (lid & 7u) * (nwg >> 3) + (lid >> 3);
  unsigned zi = swzb / gxy;
  unsigned rem = swzb % gxy;
  int row0 = (int)(rem / gx) * 128;
  int col0 = (int)(rem % gx) * 128;
  ZArg Z = (zi == 0) ? za : (zi == 1) ? zb : zc;
  gemm128_body(Z.A, Z.lda, Z.Bt, Z.ldb, Z.C, ldc, Z.mode, row0, col0, Z.K);
}

// ======================= MFMA flash attention (bf16, LDS-staged) ============
// 8 waves (512 thr), causal-pair balancing.
__global__ __launch_bounds__(512) void flash_mfma_kernel(
    const bf16_t* __restrict__ Q, const bf16_t* __restrict__ K,
    const bf16_t* __restrict__ Vt, bf16_t* __restrict__ O)
{
  __shared__ bf16_t Ks[2][64 * 64];
  __shared__ bf16_t Vs[2][64 * 64];
  __shared__ bf16_t Pl[8][32 * 64];

  int tid = threadIdx.x;
  int wave = tid >> 6, lane = tid & 63;
  int fr = lane & 15, fq = lane >> 4;
  unsigned lid = blockIdx.x + blockIdx.y * 4 + blockIdx.z * 64;  // 256 wgs
  unsigned swz8 = (lid & 7u) * 32 + (lid >> 3);
  int s_slot = swz8 & 3;
  unsigned hb = swz8 >> 2;
  int h = hb & 15, b = hb >> 4;
  int half = wave >> 2, w4 = wave & 3;
  int qb = half ? (7 - s_slot) : s_slot;
  int q0w = qb * 128 + w4 * 32;
  int KT = 16 - 2 * s_slot;
  size_t qkbase = ((size_t)b * 1024) * 1024 + (size_t)h * 64;
  size_t vtbase = ((size_t)b * 1024 + (size_t)h * 64) * 1024;

  int srow8 = lane >> 3;
  int scb = (((lane & 7) << 4) ^ (srow8 << 4)) >> 1;

#define FSTAGE(buf, kt)                                                     \
  {                                                                         \
    int k0s = (kt) * 64;                                                    \
    int row = wave * 8 + srow8;                                             \
    GLDS16(&K[qkbase + (size_t)(k0s + row) * 1024 + scb],                   \
           &Ks[buf][wave * 512]);                                           \
    GLDS16(&Vt[vtbase + (size_t)row * 1024 + k0s + scb],                    \
           &Vs[buf][wave * 512]);                                           \
  }

  bf16x8 qf[2][2];
#pragma unroll
  for (int g = 0; g < 2; g++)
#pragma unroll
    for (int kh = 0; kh < 2; kh++)
      qf[g][kh] = *(const bf16x8*)&Q[qkbase +
                                     (size_t)(q0w + g * 16 + fr) * 1024 +
                                     kh * 32 + fq * 8];

  f32x4 o_acc[2][4] = {};
  float mrow[2][4], lrow[2][4];
#pragma unroll
  for (int g = 0; g < 2; g++)
#pragma unroll
    for (int r = 0; r < 4; r++) { mrow[g][r] = -INFINITY; lrow[g][r] = 0.f; }

  char* P = (char*)&Pl[wave][0];

  FSTAGE(0, 0);

  for (int kt = 0; kt < KT; kt++) {
    __syncthreads();
    if (kt + 1 < KT) FSTAGE((kt + 1) & 1, kt + 1);
    int k0 = kt * 64;
    if (k0 <= q0w + 31) {
      const char* Kb = (const char*)&Ks[kt & 1][0];
      const char* Vb = (const char*)&Vs[kt & 1][0];
      int swz = (fr & 7) << 4;
      f32x4 s[2][4] = {};
#pragma unroll
      for (int n = 0; n < 4; n++) {
        int rowo = (n * 16 + fr) * 128;
        bf16x8 kf0 = *(const bf16x8*)(Kb + rowo + ((fq * 16) ^ swz));
        bf16x8 kf1 = *(const bf16x8*)(Kb + rowo + ((64 + fq * 16) ^ swz));
#pragma unroll
        for (int g = 0; g < 2; g++) {
          s[g][n] = __builtin_amdgcn_mfma_f32_16x16x32_bf16(qf[g][0], kf0,
                                                            s[g][n], 0, 0, 0);
          s[g][n] = __builtin_amdgcn_mfma_f32_16x16x32_bf16(qf[g][1], kf1,
                                                            s[g][n], 0, 0, 0);
        }
      }
      const float scale = 0.125f;
#pragma unroll
      for (int g = 0; g < 2; g++) {
        bool dm = (k0 + 63 > q0w + g * 16);
#pragma unroll
        for (int n = 0; n < 4; n++)
#pragma unroll
          for (int r = 0; r < 4; r++) {
            float v = s[g][n][r] * scale;
            if (dm && (k0 + n * 16 + fr > q0w + g * 16 + fq * 4 + r))
              v = -INFINITY;
            s[g][n][r] = v;
          }
      }
      float corr[2][4];
#pragma unroll
      for (int g = 0; g < 2; g++)
#pragma unroll
        for (int r = 0; r < 4; r++) {
          float mx = fmaxf(fmaxf(s[g][0][r], s[g][1][r]),
                           fmaxf(s[g][2][r], s[g][3][r]));
#pragma unroll
          for (int msk = 1; msk < 16; msk <<= 1)
            mx = fmaxf(mx, __shfl_xor(mx, msk));
          float mnew = fmaxf(mrow[g][r], mx);
          corr[g][r] = __expf(mrow[g][r] - mnew);
          mrow[g][r] = mnew;
          float ps = 0.f;
#pragma unroll
          for (int n = 0; n < 4; n++) {
            float p = __expf(s[g][n][r] - mnew);
            s[g][n][r] = p;
            ps += p;
          }
#pragma unroll
          for (int msk = 1; msk < 16; msk <<= 1) ps += __shfl_xor(ps, msk);
          lrow[g][r] = lrow[g][r] * corr[g][r] + ps;
        }
#pragma unroll
      for (int g = 0; g < 2; g++)
#pragma unroll
        for (int n = 0; n < 4; n++)
#pragma unroll
          for (int r = 0; r < 4; r++) {
            int q = g * 16 + fq * 4 + r;
            int cb = ((n * 16 + fr) * 2) ^ ((q & 7) << 4);
            *(bf16_t*)(P + q * 128 + cb) = (bf16_t)s[g][n][r];
          }
      int rr = fr & 3;
      int srcl = (fr >> 2) << 4;
#pragma unroll
      for (int g = 0; g < 2; g++) {
        float c0 = __shfl(corr[g][0], srcl);
        float c1 = __shfl(corr[g][1], srcl);
        float c2 = __shfl(corr[g][2], srcl);
        float c3 = __shfl(corr[g][3], srcl);
        float cq = rr == 0 ? c0 : rr == 1 ? c1 : rr == 2 ? c2 : c3;
#pragma unroll
        for (int n = 0; n < 4; n++)
#pragma unroll
          for (int r = 0; r < 4; r++) o_acc[g][n][r] *= cq;
      }
#pragma unroll
      for (int c = 0; c < 2; c++) {
        bf16x8 pf[2];
#pragma unroll
        for (int g = 0; g < 2; g++)
          pf[g] = *(const bf16x8*)(P + (g * 16 + fr) * 128 +
                                   ((c * 64 + fq * 16) ^ swz));
#pragma unroll
        for (int n = 0; n < 4; n++) {
          bf16x8 vf = *(const bf16x8*)(Vb + (n * 16 + fr) * 128 +
                                       ((c * 64 + fq * 16) ^ swz));
#pragma unroll
          for (int g = 0; g < 2; g++)
            o_acc[g][n] = __builtin_amdgcn_mfma_f32_16x16x32_bf16(
                vf, pf[g], o_acc[g][n], 0, 0, 0);
        }
      }
    }
  }
  int rr = fr & 3;
  int srcl = (fr >> 2) << 4;
#pragma unroll
  for (int g = 0; g < 2; g++) {
    float l0 = __shfl(lrow[g][0], srcl);
    float l1 = __shfl(lrow[g][1], srcl);
    float l2 = __shfl(lrow[g][2], srcl);
    float l3 = __shfl(lrow[g][3], srcl);
    float lq = rr == 0 ? l0 : rr == 1 ? l1 : rr == 2 ? l2 : l3;
    float linv = 1.f / lq;
    size_t orow = qkbase + (size_t)(q0w + g * 16 + fr) * 1024;
#pragma unroll
    for (int n = 0; n < 4; n++) {
      bf16x4 ov;
#pragma unroll
      for (int r = 0; r < 4; r++) ov[r] = (bf16_t)(o_acc[g][n][r] * linv);
      *(bf16x4*)&O[orow + n * 16 + fq * 4] = ov;
    }
  }
#undef FSTAGE
}

// ======================= launch =======================

extern "C" void kernel_launch(void* const* d_in, const int* in_sizes, int n_in,
                              void* d_out, int out_size, void* d_ws,
                              size_t ws_size, hipStream_t stream) {
  (void)in_sizes; (void)n_in; (void)out_size; (void)ws_size;
  const float* x          = (const float*)d_in[0];
  const float* qk_emb     = (const float*)d_in[1];
  const float* v_emb      = (const float*)d_in[2];
  const float* know_emb   = (const float*)d_in[3];
  const float* qk_f       = (const float*)d_in[4];
  const float* qk_r       = (const float*)d_in[5];
  const float* v_f        = (const float*)d_in[6];
  const float* v_r        = (const float*)d_in[7];
  const float* know_f     = (const float*)d_in[8];
  const float* know_r     = (const float*)d_in[9];
  const float* proj_attn_k = (const float*)d_in[10];
  const float* proj_attn_b = (const float*)d_in[11];
  const float* tau_attn_k  = (const float*)d_in[12];
  const float* tau_attn_b  = (const float*)d_in[13];
  const float* proj_know_k = (const float*)d_in[14];
  const float* proj_know_b = (const float*)d_in[15];
  const float* tau_know_k  = (const float*)d_in[16];
  const float* tau_know_b  = (const float*)d_in[17];
  const float* expand_O    = (const float*)d_in[18];
  const float* ln1_scale   = (const float*)d_in[19];
  const float* ln1_bias    = (const float*)d_in[20];
  const float* ln2_scale   = (const float*)d_in[21];
  const float* ln2_bias    = (const float*)d_in[22];

  float* out = (float*)d_out;  // [T,D] + aux scalar
  float* aux = out + (size_t)T * D;

  // ---- workspace arena ----
  float* ws = (float*)d_ws;
  float* n_f   = ws;                       // 4M floats
  float* tau3  = n_f + 4194304;            // 16K
  float* gq_b  = tau3 + 16384;             // 64K
  float* gk_b  = gq_b + 65536;
  float* gv_b  = gk_b + 65536;
  float* gkn_b = gv_b + 65536;             // 128K
  float* csum  = gkn_b + 131072;           // 8192
  float* rinv  = csum + 8192;              // 4*T
  float* hQ    = rinv + 16384;             // 512K
  float* hK    = hQ + 524288;
  float* hV    = hK + 524288;
  float* qkvarena = hV + 524288;           // 12.58M floats
  float* buf_big = qkvarena + 12582912;    // 16.78M floats (67MB)

  bf16_t* Qbb = (bf16_t*)qkvarena;                 // T*1024 bf16
  bf16_t* Kbb = Qbb + (size_t)T * 1024;
  bf16_t* Vtb = Kbb + (size_t)T * 1024;            // [4][1024][1024]

  bf16_t* nb   = (bf16_t*)(buf_big + 16777216);  // T*1024
  bf16_t* hab  = nb + 4194304;                   // T*384 (know: T*128)
  bf16_t* embB = hab + 1572864;                  // 524288
  bf16_t* B2t  = embB + 524288;                  // 4096*1024
  bf16_t* wt   = B2t + 4194304;
  bf16_t* pa_t  = wt;                   // 384*1024
  bf16_t* qkr_t = pa_t + 393216;        // 1024*2048
  bf16_t* vr_t  = qkr_t + 2097152;      // 1024*2048
  bf16_t* knr_t = vr_t + 2097152;       // 1024*4096
  bf16_t* eo_t  = knr_t + 4194304;      // 1024*1024
  bf16_t* pk_t  = eo_t + 1048576;       // 128*1024
  bf16_t* B2t2  = pk_t + 131072;        // 4096*1024

  // buf_big overlays (lifetimes checked):
  bf16_t* s_qb = (bf16_t*)buf_big;                  // [T,2048] bf16 16MB
  bf16_t* s_kb = s_qb + (size_t)T * 2048;           // 16..32MB
  bf16_t* s_vb = s_kb + (size_t)T * 2048;           // 32..48MB
  bf16_t* kscb = (bf16_t*)buf_big;                  // know scores [T,4096]
  bf16_t* allh_q = (bf16_t*)buf_big;                // T*2048 bf16
  bf16_t* allh_v = allh_q + (size_t)T * 2048;
  bf16_t* avbQ = (bf16_t*)buf_big;
  bf16_t* avbK = avbQ + (size_t)T * 2048;
  bf16_t* avbV = avbK + (size_t)T * 2048;
  bf16_t* avbN = (bf16_t*)buf_big;                  // know [T,4096] bf16
  bf16_t* allh_n = (bf16_t*)(buf_big + 8388608);    // know all_h (32..64MB)
  float* kp0 = buf_big + 8388608;                   // after allh_n dead
  float* kp1 = kp0 + 4194304;
  bf16_t* attnb_b = (bf16_t*)(buf_big + 12582912);  // T*1024 bf16

  bf16_t* embQ = embB;
  bf16_t* embV = embB + 262144;

  dim3 blk(256);

  zero1_kernel<<<1, 1, 0, stream>>>(aux);

  // weight + feature-basis transposes to bf16 [N,K]
  transpose_to_bf16_kernel<<<dim3(12, 32, 1), blk, 0, stream>>>(
      proj_attn_k, pa_t, 1024, 384, 0, 0);
  transpose_to_bf16_kernel<<<dim3(32, 64, 1), blk, 0, stream>>>(
      qk_r, qkr_t, 2048, 1024, 0, 0);
  transpose_to_bf16_kernel<<<dim3(32, 64, 1), blk, 0, stream>>>(
      v_r, vr_t, 2048, 1024, 0, 0);
  transpose_to_bf16_kernel<<<dim3(32, 128, 1), blk, 0, stream>>>(
      know_r, knr_t, 4096, 1024, 0, 0);
  transpose_to_bf16_kernel<<<dim3(32, 32, 1), blk, 0, stream>>>(
      expand_O, eo_t, 1024, 1024, 0, 0);
  transpose_to_bf16_kernel<<<dim3(4, 32, 1), blk, 0, stream>>>(
      proj_know_k, pk_t, 1024, 128, 0, 0);
  transpose_to_bf16_kernel<<<dim3(4, 32, 16), blk, 0, stream>>>(
      qk_f, B2t, 1024, 128, 131072, 131072);
  transpose_to_bf16_kernel<<<dim3(4, 32, 16), blk, 0, stream>>>(
      v_f, B2t2, 1024, 128, 131072, 131072);

  // ---- attention circuit ----
  ln_kernel<<<T, blk, 0, stream>>>(x, ln1_scale, ln1_bias, n_f, nb);
  norm_rows_kernel<<<2048, 64, 0, stream>>>(qk_emb, embQ);
  norm_rows_kernel<<<2048, 64, 0, stream>>>(v_emb, embV);

  mfma_gemm_kernel<true, false, 1><<<dim3(3, 64), blk, 0, stream>>>(
      nb, 1024, pa_t, 1024, hab, 384, proj_attn_b, nullptr, 0, T, 384, 1024);
  tau_kernel<<<T, 64, 0, stream>>>(n_f, tau_attn_k, tau_attn_b, tau3, 3);

  // batched gate-score GEMMs (z = {q,k,v}, K=128) -> bf16 scores
  {
    ZArg zq{hab + 0, 384, embQ, 128, s_qb, 1, 128};
    ZArg zk{hab + 128, 384, embQ, 128, s_kb, 1, 128};
    ZArg zv{hab + 256, 384, embV, 128, s_vb, 1, 128};
    mfma_gemm128b_kernel<<<dim3(16, 32, 3), blk, 0, stream>>>(
        zq, zk, zv, 2048);
  }
  gate3b_kernel<8><<<dim3(T, 3), blk, 0, stream>>>(
      s_qb, s_kb, s_vb, tau3, gq_b, gk_b, gv_b, rinv, 2048, 16);
  hipMemsetAsync(csum, 0, 6144 * sizeof(float), stream);
  colsumb_part3_kernel<<<dim3(8, 32, 3), blk, 0, stream>>>(
      s_qb, s_kb, s_vb, tau3, rinv, 2048, csum);
  colsum_fin_kernel<<<24, blk, 0, stream>>>(csum, 2048, 1.f / 2048.f, aux);

  // batched feature GEMMs (z = {qk,v}, K=1024) -> bf16 all_h
  {
    ZArg zf1{nb, 1024, B2t, 1024, allh_q, 1, 1024};
    ZArg zf2{nb, 1024, B2t2, 1024, allh_v, 1, 1024};
    mfma_gemm128b_kernel<<<dim3(16, 32, 2), blk, 0, stream>>>(
        zf1, zf2, zf1, 2048);
  }
  wsum2b_kernel<<<dim3(T, 2), 128, 0, stream>>>(allh_q, allh_v, gq_b, gk_b,
                                                gv_b, hQ, hK, hV, 16);

  // batched avirt + batched QKV restore (128^2 tile)
  avirt3_kernel<<<dim3(T, 3), blk, 0, stream>>>(hQ, hK, hV, gq_b, gk_b, gv_b,
                                                16, avbQ, avbK, avbV, 2048);
  {
    ZArg zq{avbQ, 2048, qkr_t, 2048, Qbb, 1, 2048};
    ZArg zk{avbK, 2048, qkr_t, 2048, Kbb, 1, 2048};
    ZArg zv{avbV, 2048, vr_t, 2048, Vtb, 2, 2048};
    mfma_gemm128b_kernel<<<dim3(8, 32, 3), blk, 0, stream>>>(
        zq, zk, zv, 1024);
  }

  // MFMA flash attention (causal-paired, 512 thr) + output proj + residual
  flash_mfma_kernel<<<dim3(4, 16, 4), dim3(512), 0, stream>>>(Qbb, Kbb, Vtb,
                                                              attnb_b);
  mfma_gemm_kernel<false, true, 0><<<dim3(8, 64), blk, 0, stream>>>(
      attnb_b, 1024, eo_t, 1024, out, 1024, nullptr, x, 1024, T, 1024, 1024);

  // ---- knowledge circuit ----
  ln_kernel<<<T, blk, 0, stream>>>(out, ln2_scale, ln2_bias, n_f, nb);
  norm_rows_kernel<<<4096, 64, 0, stream>>>(know_emb, embB);
  mfma_gemm_kernel<true, false, 1><<<dim3(1, 64), blk, 0, stream>>>(
      nb, 1024, pk_t, 1024, hab, 128, proj_know_b, nullptr, 0, T, 128, 1024);
  tau_kernel<<<T, 64, 0, stream>>>(n_f, tau_know_k, tau_know_b, tau3, 1);
  transpose_to_bf16_kernel<<<dim3(4, 32, 32), blk, 0, stream>>>(
      know_f, B2t, 1024, 128, 131072, 131072);

  // merged knowledge {scores (K=128), features (K=1024)} -> bf16
  {
    ZArg zs{hab, 128, embB, 128, kscb, 1, 128};
    ZArg zf{nb, 1024, B2t, 1024, allh_n, 1, 1024};
    mfma_gemm128b_kernel<<<dim3(32, 32, 2), blk, 0, stream>>>(
        zs, zf, zs, 4096);
  }
  gateb_kernel<16><<<T, blk, 0, stream>>>(kscb, tau3, gkn_b, rinv + 3 * T,
                                          4096, 32);
  hipMemsetAsync(csum, 0, 4096 * sizeof(float), stream);
  colsumb_part_kernel<<<dim3(16, 32), blk, 0, stream>>>(
      kscb, tau3, rinv + 3 * T, 4096, csum);
  colsum_fin_kernel<<<16, blk, 0, stream>>>(csum, 4096, 1.f / 4096.f, aux);

  wsum2_kernel<<<T, 128, 0, stream>>>(allh_n, gkn_b, nullptr, hQ, nullptr, 32);

  // knowledge restore: split-K=2 -> f32 partials + combine (128^2 tile)
  avirt_kernel<<<T, blk, 0, stream>>>(hQ, gkn_b, 32, avbN, 4096);
  {
    ZArg z0{avbN, 4096, knr_t, 4096, kp0, 0, 2048};
    ZArg z1{avbN + 2048, 4096, knr_t + 2048, 4096, kp1, 0, 2048};
    mfma_gemm128b_kernel<<<dim3(8, 32, 2), blk, 0, stream>>>(
        z0, z1, z0, 1024);
  }
  combine2_kernel<<<4096, blk, 0, stream>>>(kp0, kp1, out);
}

// Round 16
// 567.598 us; speedup vs baseline: 1.0286x; 1.0286x over previous
//
#include <hip/hip_runtime.h>
#include <math.h>

static constexpr int T = 4096;   // B*S
static constexpr int D = 1024;

typedef __bf16 bf16_t;
typedef bf16_t bf16x8 __attribute__((ext_vector_type(8)));
typedef bf16_t bf16x4 __attribute__((ext_vector_type(4)));
typedef float f32x4 __attribute__((ext_vector_type(4)));

#define GLDS16(g, l)                                                        \
  __builtin_amdgcn_global_load_lds(                                         \
      (const __attribute__((address_space(1))) void*)(g),                   \
      (__attribute__((address_space(3))) void*)(l), 16, 0, 0)

// ======================= small kernels =======================

__global__ void zero1_kernel(float* p) { *p = 0.f; }

__global__ __launch_bounds__(256) void ln_kernel(
    const float* __restrict__ x, const float* __restrict__ scale,
    const float* __restrict__ bias, float* __restrict__ out_f,
    bf16_t* __restrict__ out_b)
{
  int t = blockIdx.x;
  const float* xr = x + (size_t)t * D;
  float v[4];
  float s1 = 0.f, s2 = 0.f;
#pragma unroll
  for (int i = 0; i < 4; i++) {
    v[i] = xr[threadIdx.x + i * 256];
    s1 += v[i];
    s2 += v[i] * v[i];
  }
#pragma unroll
  for (int o = 1; o < 64; o <<= 1) {
    s1 += __shfl_xor(s1, o);
    s2 += __shfl_xor(s2, o);
  }
  __shared__ float r1[4], r2[4];
  int wid = threadIdx.x >> 6;
  if ((threadIdx.x & 63) == 0) { r1[wid] = s1; r2[wid] = s2; }
  __syncthreads();
  s1 = r1[0] + r1[1] + r1[2] + r1[3];
  s2 = r2[0] + r2[1] + r2[2] + r2[3];
  float mean = s1 * (1.f / D);
  float var = s2 * (1.f / D) - mean * mean;
  float rstd = rsqrtf(var + 1e-6f);
  float* orow = out_f + (size_t)t * D;
  bf16_t* brow = out_b + (size_t)t * D;
#pragma unroll
  for (int i = 0; i < 4; i++) {
    int d = threadIdx.x + i * 256;
    float o = (v[i] - mean) * rstd * scale[d] + bias[d];
    orow[d] = o;
    brow[d] = (bf16_t)o;
  }
}

// rows of length 128, one wave per row; bf16 normalized output
__global__ __launch_bounds__(64) void norm_rows_kernel(
    const float* __restrict__ e, bf16_t* __restrict__ o)
{
  int r = blockIdx.x;
  const float* row = e + (size_t)r * 128;
  float a = row[threadIdx.x], b = row[threadIdx.x + 64];
  float ss = a * a + b * b;
#pragma unroll
  for (int m = 1; m < 64; m <<= 1) ss += __shfl_xor(ss, m);
  float inv = 1.f / (sqrtf(ss) + 1e-8f);
  bf16_t* orow = o + (size_t)r * 128;
  orow[threadIdx.x] = (bf16_t)(a * inv);
  orow[threadIdx.x + 64] = (bf16_t)(b * inv);
}

// batched: rows 0..n0-1 from e0 -> o0, rest from e1 -> o1
__global__ __launch_bounds__(64) void norm_rows2_kernel(
    const float* __restrict__ e0, bf16_t* __restrict__ o0,
    const float* __restrict__ e1, bf16_t* __restrict__ o1, int n0)
{
  int r = blockIdx.x;
  const float* row = (r < n0 ? e0 + (size_t)r * 128
                             : e1 + (size_t)(r - n0) * 128);
  bf16_t* orow = (r < n0 ? o0 + (size_t)r * 128
                         : o1 + (size_t)(r - n0) * 128);
  float a = row[threadIdx.x], b = row[threadIdx.x + 64];
  float ss = a * a + b * b;
#pragma unroll
  for (int m = 1; m < 64; m <<= 1) ss += __shfl_xor(ss, m);
  float inv = 1.f / (sqrtf(ss) + 1e-8f);
  orow[threadIdx.x] = (bf16_t)(a * inv);
  orow[threadIdx.x + 64] = (bf16_t)(b * inv);
}

// tau = n @ W + b,  W: [D, J], J in {1,3}; one wave per token (fp32)
__global__ __launch_bounds__(64) void tau_kernel(
    const float* __restrict__ n, const float* __restrict__ W,
    const float* __restrict__ b, float* __restrict__ out, int J)
{
  int t = blockIdx.x;
  const float* nr = n + (size_t)t * D;
  for (int j = 0; j < J; j++) {
    float p = 0.f;
#pragma unroll 4
    for (int i = 0; i < 16; i++) {
      int d = threadIdx.x + i * 64;
      p += nr[d] * W[d * J + j];
    }
#pragma unroll
    for (int m = 1; m < 64; m <<= 1) p += __shfl_xor(p, m);
    if (threadIdx.x == 0) out[t * J + j] = p + b[j];
  }
}

// ======== gate (bf16 scores, no write-back; emits gb + rowinv) ========
template <int PER>
__device__ __forceinline__ void gateb_body(
    const bf16_t* __restrict__ row, float tv, float* __restrict__ gb, int G,
    float* __restrict__ rowinv)
{
  int base = threadIdx.x * PER;
  float psum = 0.f;
#pragma unroll
  for (int i = 0; i < PER; i += 8) {
    bf16x8 v = *(const bf16x8*)(row + base + i);
#pragma unroll
    for (int j = 0; j < 8; j++) psum += fmaxf((float)v[j] - tv, 0.f);
  }
  __shared__ float red[4];
  __shared__ float grp[32];
  if (threadIdx.x < 32) grp[threadIdx.x] = 0.f;
  float w = psum;
#pragma unroll
  for (int m = 1; m < 64; m <<= 1) w += __shfl_xor(w, m);
  int wid = threadIdx.x >> 6;
  if ((threadIdx.x & 63) == 0) red[wid] = w;
  __syncthreads();
  float Stot = red[0] + red[1] + red[2] + red[3];
  atomicAdd(&grp[base >> 7], psum);
  __syncthreads();
  float inv = 1.f / (Stot + 1e-8f);
  if (threadIdx.x == 0) *rowinv = inv;
  if (threadIdx.x < G) {
    float Gj = grp[threadIdx.x] * inv;
    float gsum = Stot * inv;
    gb[threadIdx.x] = Gj / (gsum + 1e-8f);
  }
}

template <int PER>
__global__ __launch_bounds__(256) void gate3b_kernel(
    const bf16_t* __restrict__ s0, const bf16_t* __restrict__ s1,
    const bf16_t* __restrict__ s2, const float* __restrict__ tau,
    float* __restrict__ g0, float* __restrict__ g1, float* __restrict__ g2,
    float* __restrict__ ri, int N, int G)
{
  int t = blockIdx.x, y = blockIdx.y;
  const bf16_t* g = y == 0 ? s0 : y == 1 ? s1 : s2;
  float* gb = y == 0 ? g0 : y == 1 ? g1 : g2;
  gateb_body<PER>(g + (size_t)t * N, tau[t * 3 + y], gb + (size_t)t * G, G,
                  ri + (size_t)y * T + t);
}

template <int PER>
__global__ __launch_bounds__(256) void gateb_kernel(
    const bf16_t* __restrict__ s, const float* __restrict__ tau,
    float* __restrict__ gb, float* __restrict__ ri, int N, int G)
{
  int t = blockIdx.x;
  gateb_body<PER>(s + (size_t)t * N, tau[t], gb + (size_t)t * G, G, ri + t);
}

// column partial sums of normalized gates, recomputed from bf16 scores
__global__ __launch_bounds__(256) void colsumb_part3_kernel(
    const bf16_t* __restrict__ s0, const bf16_t* __restrict__ s1,
    const bf16_t* __restrict__ s2, const float* __restrict__ tau,
    const float* __restrict__ ri, int N, float* __restrict__ colsum)
{
  int z = blockIdx.z;
  const bf16_t* g = z == 0 ? s0 : z == 1 ? s1 : s2;
  const float* riz = ri + (size_t)z * T;
  int c = blockIdx.x * 256 + threadIdx.x;
  int r0 = blockIdx.y * 128;
  float s = 0.f;
#pragma unroll 4
  for (int t = 0; t < 128; t++) {
    int row = r0 + t;
    float v = (float)g[(size_t)row * N + c];
    s += fmaxf(v - tau[row * 3 + z], 0.f) * riz[row];
  }
  atomicAdd(&colsum[z * N + c], s);
}

__global__ __launch_bounds__(256) void colsumb_part_kernel(
    const bf16_t* __restrict__ g, const float* __restrict__ tau,
    const float* __restrict__ ri, int N, float* __restrict__ colsum)
{
  int c = blockIdx.x * 256 + threadIdx.x;
  int r0 = blockIdx.y * 128;
  float s = 0.f;
#pragma unroll 4
  for (int t = 0; t < 128; t++) {
    int row = r0 + t;
    float v = (float)g[(size_t)row * N + c];
    s += fmaxf(v - tau[row], 0.f) * ri[row];
  }
  atomicAdd(&colsum[c], s);
}

// stage 2: aux += sum_c (colsum[c]/T - tinv)^2 * N
__global__ __launch_bounds__(256) void colsum_fin_kernel(
    const float* __restrict__ colsum, int N, float tinv,
    float* __restrict__ aux)
{
  int c = blockIdx.x * 256 + threadIdx.x;
  float mdev = colsum[c] * (1.f / T) - tinv;
  float p = mdev * mdev * (float)N;
#pragma unroll
  for (int m = 1; m < 64; m <<= 1) p += __shfl_xor(p, m);
  __shared__ float red[4];
  if ((threadIdx.x & 63) == 0) red[threadIdx.x >> 6] = p;
  __syncthreads();
  if (threadIdx.x == 0) atomicAdd(aux, red[0] + red[1] + red[2] + red[3]);
}

// h1[t,r] = sum_n gb1[t,n]*all_h[t, n*128+r] (all_h bf16); optional 2nd out
__global__ __launch_bounds__(128) void wsum2_kernel(
    const bf16_t* __restrict__ all_h, const float* __restrict__ gb1,
    const float* __restrict__ gb2, float* __restrict__ h1,
    float* __restrict__ h2, int NB)
{
  int t = blockIdx.x;
  int r = threadIdx.x;
  const bf16_t* row = all_h + (size_t)t * NB * 128;
  float a1 = 0.f, a2 = 0.f;
  for (int n = 0; n < NB; n++) {
    float v = (float)row[n * 128 + r];
    a1 += gb1[(size_t)t * NB + n] * v;
    if (gb2) a2 += gb2[(size_t)t * NB + n] * v;
  }
  h1[(size_t)t * 128 + r] = a1;
  if (h2) h2[(size_t)t * 128 + r] = a2;
}

__global__ __launch_bounds__(128) void wsum2b_kernel(
    const bf16_t* __restrict__ aq, const bf16_t* __restrict__ av,
    const float* __restrict__ gq, const float* __restrict__ gk,
    const float* __restrict__ gv, float* __restrict__ hQ,
    float* __restrict__ hK, float* __restrict__ hV, int NB)
{
  int t = blockIdx.x, y = blockIdx.y;
  int r = threadIdx.x;
  const bf16_t* row = (y == 0 ? aq : av) + (size_t)t * NB * 128;
  const float* g1 = (y == 0 ? gq : gv) + (size_t)t * NB;
  const float* g2 = y == 0 ? gk + (size_t)t * NB : nullptr;
  float a1 = 0.f, a2 = 0.f;
  for (int n = 0; n < NB; n++) {
    float v = (float)row[n * 128 + r];
    a1 += g1[n] * v;
    if (g2) a2 += g2[n] * v;
  }
  if (y == 0) {
    hQ[(size_t)t * 128 + r] = a1;
    hK[(size_t)t * 128 + r] = a2;
  } else {
    hV[(size_t)t * 128 + r] = a1;
  }
}

// dst[c][r] = (bf16)src[r][c]; src [R,C] fp32, dst [C,R] bf16; batched
__global__ __launch_bounds__(256) void transpose_to_bf16_kernel(
    const float* __restrict__ src, bf16_t* __restrict__ dst,
    int R, int C, size_t sbs, size_t dbs)
{
  __shared__ float tile[32][33];
  int b = blockIdx.z;
  int c0 = blockIdx.x * 32, r0 = blockIdx.y * 32;
  int tx = threadIdx.x & 31, ty = threadIdx.x >> 5;
  const float* s = src + (size_t)b * sbs;
  bf16_t* d = dst + (size_t)b * dbs;
#pragma unroll
  for (int i = 0; i < 4; i++)
    tile[ty + i * 8][tx] = s[(size_t)(r0 + ty + i * 8) * C + c0 + tx];
  __syncthreads();
#pragma unroll
  for (int i = 0; i < 4; i++)
    d[(size_t)(c0 + ty + i * 8) * R + r0 + tx] = (bf16_t)tile[tx][ty + i * 8];
}

// A_virt[t,k] = (bf16)(gb[t,k>>7]*h[t,k&127]), row-major [T,K]
__device__ __forceinline__ void avirt_body(
    const float* hr, const float* gr, bf16_t* ar, int K)
{
  int noct = K >> 3;
  for (int o = threadIdx.x; o < noct; o += 256) {
    int k = o * 8;
    float g = gr[k >> 7];
    bf16x8 v;
#pragma unroll
    for (int i = 0; i < 8; i++) v[i] = (bf16_t)(hr[(k & 127) + i] * g);
    *(bf16x8*)(ar + k) = v;
  }
}

__global__ __launch_bounds__(256) void avirt_kernel(
    const float* __restrict__ h, const float* __restrict__ gb, int NB,
    bf16_t* __restrict__ A, int K)
{
  int t = blockIdx.x;
  avirt_body(h + (size_t)t * 128, gb + (size_t)t * NB, A + (size_t)t * K, K);
}

__global__ __launch_bounds__(256) void avirt3_kernel(
    const float* __restrict__ h0, const float* __restrict__ h1,
    const float* __restrict__ h2, const float* __restrict__ g0,
    const float* __restrict__ g1, const float* __restrict__ g2, int NB,
    bf16_t* __restrict__ A0, bf16_t* __restrict__ A1,
    bf16_t* __restrict__ A2, int K)
{
  int t = blockIdx.x, y = blockIdx.y;
  const float* h = y == 0 ? h0 : y == 1 ? h1 : h2;
  const float* g = y == 0 ? g0 : y == 1 ? g1 : g2;
  bf16_t* A = y == 0 ? A0 : y == 1 ? A1 : A2;
  avirt_body(h + (size_t)t * 128, g + (size_t)t * NB, A + (size_t)t * K, K);
}

// out[i] += (float)p0[i] + (float)p1[i]  (bf16 partials, 8/thread)
__global__ __launch_bounds__(256) void combine2b_kernel(
    const bf16_t* __restrict__ p0, const bf16_t* __restrict__ p1,
    float* __restrict__ out)
{
  int i = (blockIdx.x * 256 + threadIdx.x) * 8;
  bf16x8 a = *(const bf16x8*)(p0 + i);
  bf16x8 b = *(const bf16x8*)(p1 + i);
  float4 o0 = ((float4*)(out + i))[0];
  float4 o1 = ((float4*)(out + i))[1];
  o0.x += (float)a[0] + (float)b[0];
  o0.y += (float)a[1] + (float)b[1];
  o0.z += (float)a[2] + (float)b[2];
  o0.w += (float)a[3] + (float)b[3];
  o1.x += (float)a[4] + (float)b[4];
  o1.y += (float)a[5] + (float)b[5];
  o1.z += (float)a[6] + (float)b[6];
  o1.w += (float)a[7] + (float)b[7];
  ((float4*)(out + i))[0] = o0;
  ((float4*)(out + i))[1] = o1;
}

// ======== epilogue helper (shared by all GEMM variants) ========
template <bool HAS_BIAS, bool HAS_RESID>
__device__ __forceinline__ void gemm_store(
    int mode, void* Cv, int ldc, const float* bias, const float* resid,
    int ldr, int rowb, int col, const f32x4& a)
{
  if (mode == 2) {
    bf16x4 v4;
#pragma unroll
    for (int r = 0; r < 4; r++) v4[r] = (bf16_t)a[r];
    bf16_t* dst = (bf16_t*)Cv +
        ((size_t)(rowb >> 10) * 1024 + col) * 1024 + (rowb & 1023);
    *(bf16x4*)dst = v4;
  } else {
#pragma unroll
    for (int r = 0; r < 4; r++) {
      int row = rowb + r;
      float v = a[r];
      if (HAS_BIAS) v += bias[col];
      if (HAS_RESID) v += resid[(size_t)row * ldr + col];
      if (mode == 1)
        ((bf16_t*)Cv)[(size_t)row * ldc + col] = (bf16_t)v;
      else
        ((float*)Cv)[(size_t)row * ldc + col] = v;
    }
  }
}

// ============== MFMA GEMM (64x128 tile) — narrow-N dispatches ==============
template <bool HAS_BIAS, bool HAS_RESID, int OUT_MODE>
__global__ __launch_bounds__(256) void mfma_gemm_kernel(
    const bf16_t* __restrict__ A, int lda,
    const bf16_t* __restrict__ Bt, int ldb,
    void* __restrict__ Cv, int ldc,
    const float* __restrict__ bias,
    const float* __restrict__ resid, int ldr,
    int M, int N, int K)
{
  __shared__ bf16_t As[2][64 * 32];
  __shared__ bf16_t Bs[2][128 * 32];
  int tid = threadIdx.x;
  int wave = tid >> 6, lane = tid & 63;

  unsigned lid = blockIdx.y * gridDim.x + blockIdx.x;
  unsigned nwg = gridDim.x * gridDim.y;
  unsigned swzb = lid;
  if ((nwg & 7u) == 0u) swzb = (lid & 7u) * (nwg >> 3) + (lid >> 3);
  int row0 = (int)(swzb / gridDim.x) * 64;
  int col0 = (int)(swzb % gridDim.x) * 128;

  int wr = (wave >> 1) * 32, wc = (wave & 1) * 64;
  f32x4 acc[2][4] = {};

  int srow = (wave << 4) + (lane >> 2);
  int g8 = (((lane & 3) ^ ((srow >> 1) & 3)) << 3);
  const bf16_t* gA = A + (size_t)(row0 + srow) * lda + g8;
  const bf16_t* gB = Bt + (size_t)(col0 + srow) * ldb + g8;
  size_t b64 = (size_t)64 * ldb;

  int fr = lane & 15, fq = lane >> 4;

#define GSTAGE(buf, k0s)                                  \
  {                                                       \
    GLDS16(gA + (k0s), &As[buf][wave * 512]);             \
    GLDS16(gB + (k0s), &Bs[buf][wave * 512]);             \
    GLDS16(gB + b64 + (k0s), &Bs[buf][2048 + wave * 512]);\
  }

  GSTAGE(0, 0);
  int cur = 0;
  for (int k0 = 0; k0 < K; k0 += 32) {
    __syncthreads();
    if (k0 + 32 < K) GSTAGE(cur ^ 1, k0 + 32);
    bf16x8 af[2], bfr[4];
#pragma unroll
    for (int m = 0; m < 2; m++) {
      int R = wr + m * 16 + fr;
      af[m] = *(const bf16x8*)&As[cur][R * 32 + ((fq ^ ((R >> 1) & 3)) << 3)];
    }
#pragma unroll
    for (int n = 0; n < 4; n++) {
      int R = wc + n * 16 + fr;
      bfr[n] = *(const bf16x8*)&Bs[cur][R * 32 + ((fq ^ ((R >> 1) & 3)) << 3)];
    }
#pragma unroll
    for (int m = 0; m < 2; m++)
#pragma unroll
      for (int n = 0; n < 4; n++)
        acc[m][n] = __builtin_amdgcn_mfma_f32_16x16x32_bf16(af[m], bfr[n],
                                                            acc[m][n], 0, 0, 0);
    cur ^= 1;
  }
#undef GSTAGE

#pragma unroll
  for (int m = 0; m < 2; m++)
#pragma unroll
    for (int n = 0; n < 4; n++)
      gemm_store<HAS_BIAS, HAS_RESID>(
          OUT_MODE, Cv, ldc, bias, resid, ldr,
          row0 + wr + m * 16 + fq * 4, col0 + wc + n * 16 + fr, acc[m][n]);
}

// ============== MFMA GEMM (128x128 tile) — wide dispatches ==============
// Per-z heterogeneous {A, lda, Bt, ldb, C, mode, K}.
struct ZArg { const bf16_t* A; int lda; const bf16_t* Bt; int ldb;
              void* C; int mode; int K; };

__device__ __forceinline__ void gemm128_body(
    const bf16_t* __restrict__ A, int lda, const bf16_t* __restrict__ Bt,
    int ldb, void* __restrict__ Cv, int ldc, int mode, int row0, int col0,
    int K)
{
  __shared__ bf16_t As[2][128 * 32];
  __shared__ bf16_t Bs[2][128 * 32];
  int tid = threadIdx.x;
  int wave = tid >> 6, lane = tid & 63;
  int wr = (wave >> 1) * 64, wc = (wave & 1) * 64;
  f32x4 acc[4][4] = {};

  int srow = (wave << 4) + (lane >> 2);
  int g8 = (((lane & 3) ^ ((srow >> 1) & 3)) << 3);
  const bf16_t* gA = A + (size_t)(row0 + srow) * lda + g8;
  const bf16_t* gB = Bt + (size_t)(col0 + srow) * ldb + g8;
  size_t a64 = (size_t)64 * lda, b64 = (size_t)64 * ldb;

  int fr = lane & 15, fq = lane >> 4;

#define GSTAGE8(buf, k0s)                                  \
  {                                                        \
    GLDS16(gA + (k0s), &As[buf][wave * 512]);              \
    GLDS16(gA + a64 + (k0s), &As[buf][2048 + wave * 512]); \
    GLDS16(gB + (k0s), &Bs[buf][wave * 512]);              \
    GLDS16(gB + b64 + (k0s), &Bs[buf][2048 + wave * 512]); \
  }

  GSTAGE8(0, 0);
  int cur = 0;
  for (int k0 = 0; k0 < K; k0 += 32) {
    __syncthreads();
    if (k0 + 32 < K) GSTAGE8(cur ^ 1, k0 + 32);
    bf16x8 af[4], bfr[4];
#pragma unroll
    for (int m = 0; m < 4; m++) {
      int R = wr + m * 16 + fr;
      af[m] = *(const bf16x8*)&As[cur][R * 32 + ((fq ^ ((R >> 1) & 3)) << 3)];
    }
#pragma unroll
    for (int n = 0; n < 4; n++) {
      int R = wc + n * 16 + fr;
      bfr[n] = *(const bf16x8*)&Bs[cur][R * 32 + ((fq ^ ((R >> 1) & 3)) << 3)];
    }
#pragma unroll
    for (int m = 0; m < 4; m++)
#pragma unroll
      for (int n = 0; n < 4; n++)
        acc[m][n] = __builtin_amdgcn_mfma_f32_16x16x32_bf16(af[m], bfr[n],
                                                            acc[m][n], 0, 0, 0);
    cur ^= 1;
  }
#undef GSTAGE8

#pragma unroll
  for (int m = 0; m < 4; m++)
#pragma unroll
    for (int n = 0; n < 4; n++)
      gemm_store<false, false>(
          mode, Cv, ldc, nullptr, nullptr, 0,
          row0 + wr + m * 16 + fq * 4, col0 + wc + n * 16 + fr, acc[m][n]);
}

__global__ __launch_bounds__(256) void mfma_gemm128b_kernel(
    ZArg za, ZArg zb, ZArg zc, int ldc)
{
  unsigned gx = gridDim.x;
  unsigned gxy = gridDim.x * gridDim.y;
  unsigned lid = (blockIdx.z * gridDim.y + blockIdx.y) * gx + blockIdx.x;
  unsigned nwg = gxy * gridDim.z;
  unsigned swzb = lid;
  if ((nwg & 7u) == 0u) swzb = (lid & 7u) * (nwg >> 3) + (lid >> 3);
  unsigned zi = swzb / gxy;
  unsigned rem = swzb % gxy;
  int row0 = (int)(rem / gx) * 128;
  int col0 = (int)(rem % gx) * 128;
  ZArg Z = (zi == 0) ? za : (zi == 1) ? zb : zc;
  gemm128_body(Z.A, Z.lda, Z.Bt, Z.ldb, Z.C, ldc, Z.mode, row0, col0, Z.K);
}

// ======================= MFMA flash attention (bf16, LDS-staged) ============
// 8 waves (512 thr), causal-pair balancing.
__global__ __launch_bounds__(512) void flash_mfma_kernel(
    const bf16_t* __restrict__ Q, const bf16_t* __restrict__ K,
    const bf16_t* __restrict__ Vt, bf16_t* __restrict__ O)
{
  __shared__ bf16_t Ks[2][64 * 64];
  __shared__ bf16_t Vs[2][64 * 64];
  __shared__ bf16_t Pl[8][32 * 64];

  int tid = threadIdx.x;
  int wave = tid >> 6, lane = tid & 63;
  int fr = lane & 15, fq = lane >> 4;
  unsigned lid = blockIdx.x + blockIdx.y * 4 + blockIdx.z * 64;  // 256 wgs
  unsigned swz8 = (lid & 7u) * 32 + (lid >> 3);
  int s_slot = swz8 & 3;
  unsigned hb = swz8 >> 2;
  int h = hb & 15, b = hb >> 4;
  int half = wave >> 2, w4 = wave & 3;
  int qb = half ? (7 - s_slot) : s_slot;
  int q0w = qb * 128 + w4 * 32;
  int KT = 16 - 2 * s_slot;
  size_t qkbase = ((size_t)b * 1024) * 1024 + (size_t)h * 64;
  size_t vtbase = ((size_t)b * 1024 + (size_t)h * 64) * 1024;

  int srow8 = lane >> 3;
  int scb = (((lane & 7) << 4) ^ (srow8 << 4)) >> 1;

#define FSTAGE(buf, kt)                                                     \
  {                                                                         \
    int k0s = (kt) * 64;                                                    \
    int row = wave * 8 + srow8;                                             \
    GLDS16(&K[qkbase + (size_t)(k0s + row) * 1024 + scb],                   \
           &Ks[buf][wave * 512]);                                           \
    GLDS16(&Vt[vtbase + (size_t)row * 1024 + k0s + scb],                    \
           &Vs[buf][wave * 512]);                                           \
  }

  bf16x8 qf[2][2];
#pragma unroll
  for (int g = 0; g < 2; g++)
#pragma unroll
    for (int kh = 0; kh < 2; kh++)
      qf[g][kh] = *(const bf16x8*)&Q[qkbase +
                                     (size_t)(q0w + g * 16 + fr) * 1024 +
                                     kh * 32 + fq * 8];

  f32x4 o_acc[2][4] = {};
  float mrow[2][4], lrow[2][4];
#pragma unroll
  for (int g = 0; g < 2; g++)
#pragma unroll
    for (int r = 0; r < 4; r++) { mrow[g][r] = -INFINITY; lrow[g][r] = 0.f; }

  char* P = (char*)&Pl[wave][0];

  FSTAGE(0, 0);

  for (int kt = 0; kt < KT; kt++) {
    __syncthreads();
    if (kt + 1 < KT) FSTAGE((kt + 1) & 1, kt + 1);
    int k0 = kt * 64;
    if (k0 <= q0w + 31) {
      const char* Kb = (const char*)&Ks[kt & 1][0];
      const char* Vb = (const char*)&Vs[kt & 1][0];
      int swz = (fr & 7) << 4;
      f32x4 s[2][4] = {};
#pragma unroll
      for (int n = 0; n < 4; n++) {
        int rowo = (n * 16 + fr) * 128;
        bf16x8 kf0 = *(const bf16x8*)(Kb + rowo + ((fq * 16) ^ swz));
        bf16x8 kf1 = *(const bf16x8*)(Kb + rowo + ((64 + fq * 16) ^ swz));
#pragma unroll
        for (int g = 0; g < 2; g++) {
          s[g][n] = __builtin_amdgcn_mfma_f32_16x16x32_bf16(qf[g][0], kf0,
                                                            s[g][n], 0, 0, 0);
          s[g][n] = __builtin_amdgcn_mfma_f32_16x16x32_bf16(qf[g][1], kf1,
                                                            s[g][n], 0, 0, 0);
        }
      }
      const float scale = 0.125f;
#pragma unroll
      for (int g = 0; g < 2; g++) {
        bool dm = (k0 + 63 > q0w + g * 16);
#pragma unroll
        for (int n = 0; n < 4; n++)
#pragma unroll
          for (int r = 0; r < 4; r++) {
            float v = s[g][n][r] * scale;
            if (dm && (k0 + n * 16 + fr > q0w + g * 16 + fq * 4 + r))
              v = -INFINITY;
            s[g][n][r] = v;
          }
      }
      float corr[2][4];
#pragma unroll
      for (int g = 0; g < 2; g++)
#pragma unroll
        for (int r = 0; r < 4; r++) {
          float mx = fmaxf(fmaxf(s[g][0][r], s[g][1][r]),
                           fmaxf(s[g][2][r], s[g][3][r]));
#pragma unroll
          for (int msk = 1; msk < 16; msk <<= 1)
            mx = fmaxf(mx, __shfl_xor(mx, msk));
          float mnew = fmaxf(mrow[g][r], mx);
          corr[g][r] = __expf(mrow[g][r] - mnew);
          mrow[g][r] = mnew;
          float ps = 0.f;
#pragma unroll
          for (int n = 0; n < 4; n++) {
            float p = __expf(s[g][n][r] - mnew);
            s[g][n][r] = p;
            ps += p;
          }
#pragma unroll
          for (int msk = 1; msk < 16; msk <<= 1) ps += __shfl_xor(ps, msk);
          lrow[g][r] = lrow[g][r] * corr[g][r] + ps;
        }
#pragma unroll
      for (int g = 0; g < 2; g++)
#pragma unroll
        for (int n = 0; n < 4; n++)
#pragma unroll
          for (int r = 0; r < 4; r++) {
            int q = g * 16 + fq * 4 + r;
            int cb = ((n * 16 + fr) * 2) ^ ((q & 7) << 4);
            *(bf16_t*)(P + q * 128 + cb) = (bf16_t)s[g][n][r];
          }
      int rr = fr & 3;
      int srcl = (fr >> 2) << 4;
#pragma unroll
      for (int g = 0; g < 2; g++) {
        float c0 = __shfl(corr[g][0], srcl);
        float c1 = __shfl(corr[g][1], srcl);
        float c2 = __shfl(corr[g][2], srcl);
        float c3 = __shfl(corr[g][3], srcl);
        float cq = rr == 0 ? c0 : rr == 1 ? c1 : rr == 2 ? c2 : c3;
#pragma unroll
        for (int n = 0; n < 4; n++)
#pragma unroll
          for (int r = 0; r < 4; r++) o_acc[g][n][r] *= cq;
      }
#pragma unroll
      for (int c = 0; c < 2; c++) {
        bf16x8 pf[2];
#pragma unroll
        for (int g = 0; g < 2; g++)
          pf[g] = *(const bf16x8*)(P + (g * 16 + fr) * 128 +
                                   ((c * 64 + fq * 16) ^ swz));
#pragma unroll
        for (int n = 0; n < 4; n++) {
          bf16x8 vf = *(const bf16x8*)(Vb + (n * 16 + fr) * 128 +
                                       ((c * 64 + fq * 16) ^ swz));
#pragma unroll
          for (int g = 0; g < 2; g++)
            o_acc[g][n] = __builtin_amdgcn_mfma_f32_16x16x32_bf16(
                vf, pf[g], o_acc[g][n], 0, 0, 0);
        }
      }
    }
  }
  int rr = fr & 3;
  int srcl = (fr >> 2) << 4;
#pragma unroll
  for (int g = 0; g < 2; g++) {
    float l0 = __shfl(lrow[g][0], srcl);
    float l1 = __shfl(lrow[g][1], srcl);
    float l2 = __shfl(lrow[g][2], srcl);
    float l3 = __shfl(lrow[g][3], srcl);
    float lq = rr == 0 ? l0 : rr == 1 ? l1 : rr == 2 ? l2 : l3;
    float linv = 1.f / lq;
    size_t orow = qkbase + (size_t)(q0w + g * 16 + fr) * 1024;
#pragma unroll
    for (int n = 0; n < 4; n++) {
      bf16x4 ov;
#pragma unroll
      for (int r = 0; r < 4; r++) ov[r] = (bf16_t)(o_acc[g][n][r] * linv);
      *(bf16x4*)&O[orow + n * 16 + fq * 4] = ov;
    }
  }
#undef FSTAGE
}

// ======================= launch =======================

extern "C" void kernel_launch(void* const* d_in, const int* in_sizes, int n_in,
                              void* d_out, int out_size, void* d_ws,
                              size_t ws_size, hipStream_t stream) {
  (void)in_sizes; (void)n_in; (void)out_size; (void)ws_size;
  const float* x          = (const float*)d_in[0];
  const float* qk_emb     = (const float*)d_in[1];
  const float* v_emb      = (const float*)d_in[2];
  const float* know_emb   = (const float*)d_in[3];
  const float* qk_f       = (const float*)d_in[4];
  const float* qk_r       = (const float*)d_in[5];
  const float* v_f        = (const float*)d_in[6];
  const float* v_r        = (const float*)d_in[7];
  const float* know_f     = (const float*)d_in[8];
  const float* know_r     = (const float*)d_in[9];
  const float* proj_attn_k = (const float*)d_in[10];
  const float* proj_attn_b = (const float*)d_in[11];
  const float* tau_attn_k  = (const float*)d_in[12];
  const float* tau_attn_b  = (const float*)d_in[13];
  const float* proj_know_k = (const float*)d_in[14];
  const float* proj_know_b = (const float*)d_in[15];
  const float* tau_know_k  = (const float*)d_in[16];
  const float* tau_know_b  = (const float*)d_in[17];
  const float* expand_O    = (const float*)d_in[18];
  const float* ln1_scale   = (const float*)d_in[19];
  const float* ln1_bias    = (const float*)d_in[20];
  const float* ln2_scale   = (const float*)d_in[21];
  const float* ln2_bias    = (const float*)d_in[22];

  float* out = (float*)d_out;  // [T,D] + aux scalar
  float* aux = out + (size_t)T * D;

  // ---- workspace arena ----
  float* ws = (float*)d_ws;
  float* n_f   = ws;                       // 4M floats
  float* tau3  = n_f + 4194304;            // 16K
  float* gq_b  = tau3 + 16384;             // 64K
  float* gk_b  = gq_b + 65536;
  float* gv_b  = gk_b + 65536;
  float* gkn_b = gv_b + 65536;             // 128K
  float* csum  = gkn_b + 131072;           // 8192
  float* rinv  = csum + 8192;              // 4*T
  float* hQ    = rinv + 16384;             // 512K
  float* hK    = hQ + 524288;
  float* hV    = hK + 524288;
  float* qkvarena = hV + 524288;           // 12.58M floats
  float* buf_big = qkvarena + 12582912;    // 16.78M floats (67MB)

  bf16_t* Qbb = (bf16_t*)qkvarena;                 // T*1024 bf16
  bf16_t* Kbb = Qbb + (size_t)T * 1024;
  bf16_t* Vtb = Kbb + (size_t)T * 1024;            // [4][1024][1024]

  bf16_t* nb   = (bf16_t*)(buf_big + 16777216);  // T*1024
  bf16_t* hab  = nb + 4194304;                   // T*384 (know: T*128)
  bf16_t* embB = hab + 1572864;                  // 524288
  bf16_t* B2t  = embB + 524288;                  // 4096*1024
  bf16_t* wt   = B2t + 4194304;
  bf16_t* pa_t  = wt;                   // 384*1024
  bf16_t* qkr_t = pa_t + 393216;        // 1024*2048
  bf16_t* vr_t  = qkr_t + 2097152;      // 1024*2048
  bf16_t* knr_t = vr_t + 2097152;       // 1024*4096
  bf16_t* eo_t  = knr_t + 4194304;      // 1024*1024
  bf16_t* pk_t  = eo_t + 1048576;       // 128*1024
  bf16_t* B2t2  = pk_t + 131072;        // 4096*1024

  // buf_big overlays (lifetimes checked):
  bf16_t* s_qb = (bf16_t*)buf_big;                  // [T,2048] bf16 16MB
  bf16_t* s_kb = s_qb + (size_t)T * 2048;           // 16..32MB
  bf16_t* s_vb = s_kb + (size_t)T * 2048;           // 32..48MB
  bf16_t* kscb = (bf16_t*)buf_big;                  // know scores [T,4096]
  bf16_t* allh_q = (bf16_t*)buf_big;                // T*2048 bf16
  bf16_t* allh_v = allh_q + (size_t)T * 2048;
  bf16_t* avbQ = (bf16_t*)buf_big;
  bf16_t* avbK = avbQ + (size_t)T * 2048;
  bf16_t* avbV = avbK + (size_t)T * 2048;
  bf16_t* avbN = (bf16_t*)buf_big;                  // know [T,4096] bf16
  bf16_t* allh_n = (bf16_t*)buf_big;                // aliases kscb (seq.)
  bf16_t* kp0 = (bf16_t*)(buf_big + 8388608);       // bf16 partial 32..40MB
  bf16_t* kp1 = kp0 + 4194304;                      // 40..48MB
  bf16_t* attnb_b = (bf16_t*)(buf_big + 12582912);  // T*1024 bf16

  bf16_t* embQ = embB;
  bf16_t* embV = embB + 262144;

  dim3 blk(256);

  zero1_kernel<<<1, 1, 0, stream>>>(aux);

  // weight + feature-basis transposes to bf16 [N,K]
  transpose_to_bf16_kernel<<<dim3(12, 32, 1), blk, 0, stream>>>(
      proj_attn_k, pa_t, 1024, 384, 0, 0);
  transpose_to_bf16_kernel<<<dim3(32, 64, 1), blk, 0, stream>>>(
      qk_r, qkr_t, 2048, 1024, 0, 0);
  transpose_to_bf16_kernel<<<dim3(32, 64, 1), blk, 0, stream>>>(
      v_r, vr_t, 2048, 1024, 0, 0);
  transpose_to_bf16_kernel<<<dim3(32, 128, 1), blk, 0, stream>>>(
      know_r, knr_t, 4096, 1024, 0, 0);
  transpose_to_bf16_kernel<<<dim3(32, 32, 1), blk, 0, stream>>>(
      expand_O, eo_t, 1024, 1024, 0, 0);
  transpose_to_bf16_kernel<<<dim3(4, 32, 1), blk, 0, stream>>>(
      proj_know_k, pk_t, 1024, 128, 0, 0);
  transpose_to_bf16_kernel<<<dim3(4, 32, 16), blk, 0, stream>>>(
      qk_f, B2t, 1024, 128, 131072, 131072);
  transpose_to_bf16_kernel<<<dim3(4, 32, 16), blk, 0, stream>>>(
      v_f, B2t2, 1024, 128, 131072, 131072);

  // ---- attention circuit ----
  ln_kernel<<<T, blk, 0, stream>>>(x, ln1_scale, ln1_bias, n_f, nb);
  norm_rows2_kernel<<<4096, 64, 0, stream>>>(qk_emb, embQ, v_emb, embV, 2048);

  mfma_gemm_kernel<true, false, 1><<<dim3(3, 64), blk, 0, stream>>>(
      nb, 1024, pa_t, 1024, hab, 384, proj_attn_b, nullptr, 0, T, 384, 1024);
  tau_kernel<<<T, 64, 0, stream>>>(n_f, tau_attn_k, tau_attn_b, tau3, 3);

  // batched gate-score GEMMs (z = {q,k,v}, K=128) -> bf16 scores
  {
    ZArg zq{hab + 0, 384, embQ, 128, s_qb, 1, 128};
    ZArg zk{hab + 128, 384, embQ, 128, s_kb, 1, 128};
    ZArg zv{hab + 256, 384, embV, 128, s_vb, 1, 128};
    mfma_gemm128b_kernel<<<dim3(16, 32, 3), blk, 0, stream>>>(
        zq, zk, zv, 2048);
  }
  gate3b_kernel<8><<<dim3(T, 3), blk, 0, stream>>>(
      s_qb, s_kb, s_vb, tau3, gq_b, gk_b, gv_b, rinv, 2048, 16);
  hipMemsetAsync(csum, 0, 6144 * sizeof(float), stream);
  colsumb_part3_kernel<<<dim3(8, 32, 3), blk, 0, stream>>>(
      s_qb, s_kb, s_vb, tau3, rinv, 2048, csum);
  colsum_fin_kernel<<<24, blk, 0, stream>>>(csum, 2048, 1.f / 2048.f, aux);

  // batched feature GEMMs (z = {qk,v}, K=1024) -> bf16 all_h
  {
    ZArg zf1{nb, 1024, B2t, 1024, allh_q, 1, 1024};
    ZArg zf2{nb, 1024, B2t2, 1024, allh_v, 1, 1024};
    mfma_gemm128b_kernel<<<dim3(16, 32, 2), blk, 0, stream>>>(
        zf1, zf2, zf1, 2048);
  }
  // know_f transpose: B2t free now; fills gap before knowledge circuit
  transpose_to_bf16_kernel<<<dim3(4, 32, 32), blk, 0, stream>>>(
      know_f, B2t, 1024, 128, 131072, 131072);
  wsum2b_kernel<<<dim3(T, 2), 128, 0, stream>>>(allh_q, allh_v, gq_b, gk_b,
                                                gv_b, hQ, hK, hV, 16);

  // batched avirt + batched QKV restore (128^2 tile)
  avirt3_kernel<<<dim3(T, 3), blk, 0, stream>>>(hQ, hK, hV, gq_b, gk_b, gv_b,
                                                16, avbQ, avbK, avbV, 2048);
  {
    ZArg zq{avbQ, 2048, qkr_t, 2048, Qbb, 1, 2048};
    ZArg zk{avbK, 2048, qkr_t, 2048, Kbb, 1, 2048};
    ZArg zv{avbV, 2048, vr_t, 2048, Vtb, 2, 2048};
    mfma_gemm128b_kernel<<<dim3(8, 32, 3), blk, 0, stream>>>(
        zq, zk, zv, 1024);
  }

  // MFMA flash attention (causal-paired, 512 thr) + output proj + residual
  flash_mfma_kernel<<<dim3(4, 16, 4), dim3(512), 0, stream>>>(Qbb, Kbb, Vtb,
                                                              attnb_b);
  mfma_gemm_kernel<false, true, 0><<<dim3(8, 64), blk, 0, stream>>>(
      attnb_b, 1024, eo_t, 1024, out, 1024, nullptr, x, 1024, T, 1024, 1024);

  // ---- knowledge circuit ----
  ln_kernel<<<T, blk, 0, stream>>>(out, ln2_scale, ln2_bias, n_f, nb);
  norm_rows_kernel<<<4096, 64, 0, stream>>>(know_emb, embB);
  mfma_gemm_kernel<true, false, 1><<<dim3(1, 64), blk, 0, stream>>>(
      nb, 1024, pk_t, 1024, hab, 128, proj_know_b, nullptr, 0, T, 128, 1024);
  tau_kernel<<<T, 64, 0, stream>>>(n_f, tau_know_k, tau_know_b, tau3, 1);

  // know scores -> bf16 (kscb in buf_big[0..32MB])
  {
    ZArg zs{hab, 128, embB, 128, kscb, 1, 128};
    mfma_gemm128b_kernel<<<dim3(32, 32, 1), blk, 0, stream>>>(
        zs, zs, zs, 4096);
  }
  gateb_kernel<16><<<T, blk, 0, stream>>>(kscb, tau3, gkn_b, rinv + 3 * T,
                                          4096, 32);
  hipMemsetAsync(csum, 0, 4096 * sizeof(float), stream);
  colsumb_part_kernel<<<dim3(16, 32), blk, 0, stream>>>(
      kscb, tau3, rinv + 3 * T, 4096, csum);
  colsum_fin_kernel<<<16, blk, 0, stream>>>(csum, 4096, 1.f / 4096.f, aux);

  // know features -> bf16 (allh_n aliases kscb; kscb dead after colsum)
  {
    ZArg zf{nb, 1024, B2t, 1024, allh_n, 1, 1024};
    mfma_gemm128b_kernel<<<dim3(32, 32, 1), blk, 0, stream>>>(
        zf, zf, zf, 4096);
  }
  wsum2_kernel<<<T, 128, 0, stream>>>(allh_n, gkn_b, nullptr, hQ, nullptr, 32);

  // knowledge restore: split-K=2 -> bf16 partials + combine (128^2 tile)
  avirt_kernel<<<T, blk, 0, stream>>>(hQ, gkn_b, 32, avbN, 4096);
  {
    ZArg z0{avbN, 4096, knr_t, 4096, kp0, 1, 2048};
    ZArg z1{avbN + 2048, 4096, knr_t + 2048, 4096, kp1, 1, 2048};
    mfma_gemm128b_kernel<<<dim3(8, 32, 2), blk, 0, stream>>>(
        z0, z1, z0, 1024);
  }
  combine2b_kernel<<<2048, blk, 0, stream>>>(kp0, kp1, out);
}

// Round 17
// 543.821 us; speedup vs baseline: 1.0735x; 1.0437x over previous
//
#include <hip/hip_runtime.h>
#include <math.h>

static constexpr int T = 4096;   // B*S
static constexpr int D = 1024;

typedef __bf16 bf16_t;
typedef bf16_t bf16x8 __attribute__((ext_vector_type(8)));
typedef bf16_t bf16x4 __attribute__((ext_vector_type(4)));
typedef float f32x4 __attribute__((ext_vector_type(4)));

#define GLDS16(g, l)                                                        \
  __builtin_amdgcn_global_load_lds(                                         \
      (const __attribute__((address_space(1))) void*)(g),                   \
      (__attribute__((address_space(3))) void*)(l), 16, 0, 0)

// ======================= small kernels =======================

__global__ void zero1_kernel(float* p) { *p = 0.f; }

__global__ __launch_bounds__(256) void ln_kernel(
    const float* __restrict__ x, const float* __restrict__ scale,
    const float* __restrict__ bias, float* __restrict__ out_f,
    bf16_t* __restrict__ out_b)
{
  int t = blockIdx.x;
  const float* xr = x + (size_t)t * D;
  float v[4];
  float s1 = 0.f, s2 = 0.f;
#pragma unroll
  for (int i = 0; i < 4; i++) {
    v[i] = xr[threadIdx.x + i * 256];
    s1 += v[i];
    s2 += v[i] * v[i];
  }
#pragma unroll
  for (int o = 1; o < 64; o <<= 1) {
    s1 += __shfl_xor(s1, o);
    s2 += __shfl_xor(s2, o);
  }
  __shared__ float r1[4], r2[4];
  int wid = threadIdx.x >> 6;
  if ((threadIdx.x & 63) == 0) { r1[wid] = s1; r2[wid] = s2; }
  __syncthreads();
  s1 = r1[0] + r1[1] + r1[2] + r1[3];
  s2 = r2[0] + r2[1] + r2[2] + r2[3];
  float mean = s1 * (1.f / D);
  float var = s2 * (1.f / D) - mean * mean;
  float rstd = rsqrtf(var + 1e-6f);
  float* orow = out_f + (size_t)t * D;
  bf16_t* brow = out_b + (size_t)t * D;
#pragma unroll
  for (int i = 0; i < 4; i++) {
    int d = threadIdx.x + i * 256;
    float o = (v[i] - mean) * rstd * scale[d] + bias[d];
    orow[d] = o;
    brow[d] = (bf16_t)o;
  }
}

// rows of length 128, one wave per row; bf16 normalized output
__global__ __launch_bounds__(64) void norm_rows_kernel(
    const float* __restrict__ e, bf16_t* __restrict__ o)
{
  int r = blockIdx.x;
  const float* row = e + (size_t)r * 128;
  float a = row[threadIdx.x], b = row[threadIdx.x + 64];
  float ss = a * a + b * b;
#pragma unroll
  for (int m = 1; m < 64; m <<= 1) ss += __shfl_xor(ss, m);
  float inv = 1.f / (sqrtf(ss) + 1e-8f);
  bf16_t* orow = o + (size_t)r * 128;
  orow[threadIdx.x] = (bf16_t)(a * inv);
  orow[threadIdx.x + 64] = (bf16_t)(b * inv);
}

// batched: rows 0..n0-1 from e0 -> o0, rest from e1 -> o1
__global__ __launch_bounds__(64) void norm_rows2_kernel(
    const float* __restrict__ e0, bf16_t* __restrict__ o0,
    const float* __restrict__ e1, bf16_t* __restrict__ o1, int n0)
{
  int r = blockIdx.x;
  const float* row = (r < n0 ? e0 + (size_t)r * 128
                             : e1 + (size_t)(r - n0) * 128);
  bf16_t* orow = (r < n0 ? o0 + (size_t)r * 128
                         : o1 + (size_t)(r - n0) * 128);
  float a = row[threadIdx.x], b = row[threadIdx.x + 64];
  float ss = a * a + b * b;
#pragma unroll
  for (int m = 1; m < 64; m <<= 1) ss += __shfl_xor(ss, m);
  float inv = 1.f / (sqrtf(ss) + 1e-8f);
  orow[threadIdx.x] = (bf16_t)(a * inv);
  orow[threadIdx.x + 64] = (bf16_t)(b * inv);
}

// tau = n @ W + b,  W: [D, J], J in {1,3}; one wave per token (fp32)
__global__ __launch_bounds__(64) void tau_kernel(
    const float* __restrict__ n, const float* __restrict__ W,
    const float* __restrict__ b, float* __restrict__ out, int J)
{
  int t = blockIdx.x;
  const float* nr = n + (size_t)t * D;
  for (int j = 0; j < J; j++) {
    float p = 0.f;
#pragma unroll 4
    for (int i = 0; i < 16; i++) {
      int d = threadIdx.x + i * 64;
      p += nr[d] * W[d * J + j];
    }
#pragma unroll
    for (int m = 1; m < 64; m <<= 1) p += __shfl_xor(p, m);
    if (threadIdx.x == 0) out[t * J + j] = p + b[j];
  }
}

// ======== gate (bf16 scores, no write-back; emits gb + rowinv) ========
template <int PER>
__device__ __forceinline__ void gateb_body(
    const bf16_t* __restrict__ row, float tv, float* __restrict__ gb, int G,
    float* __restrict__ rowinv)
{
  int base = threadIdx.x * PER;
  float psum = 0.f;
#pragma unroll
  for (int i = 0; i < PER; i += 8) {
    bf16x8 v = *(const bf16x8*)(row + base + i);
#pragma unroll
    for (int j = 0; j < 8; j++) psum += fmaxf((float)v[j] - tv, 0.f);
  }
  __shared__ float red[4];
  __shared__ float grp[32];
  if (threadIdx.x < 32) grp[threadIdx.x] = 0.f;
  float w = psum;
#pragma unroll
  for (int m = 1; m < 64; m <<= 1) w += __shfl_xor(w, m);
  int wid = threadIdx.x >> 6;
  if ((threadIdx.x & 63) == 0) red[wid] = w;
  __syncthreads();
  float Stot = red[0] + red[1] + red[2] + red[3];
  atomicAdd(&grp[base >> 7], psum);
  __syncthreads();
  float inv = 1.f / (Stot + 1e-8f);
  if (threadIdx.x == 0) *rowinv = inv;
  if (threadIdx.x < G) {
    float Gj = grp[threadIdx.x] * inv;
    float gsum = Stot * inv;
    gb[threadIdx.x] = Gj / (gsum + 1e-8f);
  }
}

template <int PER>
__global__ __launch_bounds__(256) void gate3b_kernel(
    const bf16_t* __restrict__ s0, const bf16_t* __restrict__ s1,
    const bf16_t* __restrict__ s2, const float* __restrict__ tau,
    float* __restrict__ g0, float* __restrict__ g1, float* __restrict__ g2,
    float* __restrict__ ri, int N, int G)
{
  int t = blockIdx.x, y = blockIdx.y;
  const bf16_t* g = y == 0 ? s0 : y == 1 ? s1 : s2;
  float* gb = y == 0 ? g0 : y == 1 ? g1 : g2;
  gateb_body<PER>(g + (size_t)t * N, tau[t * 3 + y], gb + (size_t)t * G, G,
                  ri + (size_t)y * T + t);
}

template <int PER>
__global__ __launch_bounds__(256) void gateb_kernel(
    const bf16_t* __restrict__ s, const float* __restrict__ tau,
    float* __restrict__ gb, float* __restrict__ ri, int N, int G)
{
  int t = blockIdx.x;
  gateb_body<PER>(s + (size_t)t * N, tau[t], gb + (size_t)t * G, G, ri + t);
}

// column partial sums of normalized gates, recomputed from bf16 scores
__global__ __launch_bounds__(256) void colsumb_part3_kernel(
    const bf16_t* __restrict__ s0, const bf16_t* __restrict__ s1,
    const bf16_t* __restrict__ s2, const float* __restrict__ tau,
    const float* __restrict__ ri, int N, float* __restrict__ colsum)
{
  int z = blockIdx.z;
  const bf16_t* g = z == 0 ? s0 : z == 1 ? s1 : s2;
  const float* riz = ri + (size_t)z * T;
  int c = blockIdx.x * 256 + threadIdx.x;
  int r0 = blockIdx.y * 128;
  float s = 0.f;
#pragma unroll 4
  for (int t = 0; t < 128; t++) {
    int row = r0 + t;
    float v = (float)g[(size_t)row * N + c];
    s += fmaxf(v - tau[row * 3 + z], 0.f) * riz[row];
  }
  atomicAdd(&colsum[z * N + c], s);
}

__global__ __launch_bounds__(256) void colsumb_part_kernel(
    const bf16_t* __restrict__ g, const float* __restrict__ tau,
    const float* __restrict__ ri, int N, float* __restrict__ colsum)
{
  int c = blockIdx.x * 256 + threadIdx.x;
  int r0 = blockIdx.y * 128;
  float s = 0.f;
#pragma unroll 4
  for (int t = 0; t < 128; t++) {
    int row = r0 + t;
    float v = (float)g[(size_t)row * N + c];
    s += fmaxf(v - tau[row], 0.f) * ri[row];
  }
  atomicAdd(&colsum[c], s);
}

// stage 2: aux += sum_c (colsum[c]/T - tinv)^2 * N
__global__ __launch_bounds__(256) void colsum_fin_kernel(
    const float* __restrict__ colsum, int N, float tinv,
    float* __restrict__ aux)
{
  int c = blockIdx.x * 256 + threadIdx.x;
  float mdev = colsum[c] * (1.f / T) - tinv;
  float p = mdev * mdev * (float)N;
#pragma unroll
  for (int m = 1; m < 64; m <<= 1) p += __shfl_xor(p, m);
  __shared__ float red[4];
  if ((threadIdx.x & 63) == 0) red[threadIdx.x >> 6] = p;
  __syncthreads();
  if (threadIdx.x == 0) atomicAdd(aux, red[0] + red[1] + red[2] + red[3]);
}

// h1[t,r] = sum_n gb1[t,n]*all_h[t, n*128+r] (all_h bf16); optional 2nd out
__global__ __launch_bounds__(128) void wsum2_kernel(
    const bf16_t* __restrict__ all_h, const float* __restrict__ gb1,
    const float* __restrict__ gb2, float* __restrict__ h1,
    float* __restrict__ h2, int NB)
{
  int t = blockIdx.x;
  int r = threadIdx.x;
  const bf16_t* row = all_h + (size_t)t * NB * 128;
  float a1 = 0.f, a2 = 0.f;
  for (int n = 0; n < NB; n++) {
    float v = (float)row[n * 128 + r];
    a1 += gb1[(size_t)t * NB + n] * v;
    if (gb2) a2 += gb2[(size_t)t * NB + n] * v;
  }
  h1[(size_t)t * 128 + r] = a1;
  if (h2) h2[(size_t)t * 128 + r] = a2;
}

__global__ __launch_bounds__(128) void wsum2b_kernel(
    const bf16_t* __restrict__ aq, const bf16_t* __restrict__ av,
    const float* __restrict__ gq, const float* __restrict__ gk,
    const float* __restrict__ gv, float* __restrict__ hQ,
    float* __restrict__ hK, float* __restrict__ hV, int NB)
{
  int t = blockIdx.x, y = blockIdx.y;
  int r = threadIdx.x;
  const bf16_t* row = (y == 0 ? aq : av) + (size_t)t * NB * 128;
  const float* g1 = (y == 0 ? gq : gv) + (size_t)t * NB;
  const float* g2 = y == 0 ? gk + (size_t)t * NB : nullptr;
  float a1 = 0.f, a2 = 0.f;
  for (int n = 0; n < NB; n++) {
    float v = (float)row[n * 128 + r];
    a1 += g1[n] * v;
    if (g2) a2 += g2[n] * v;
  }
  if (y == 0) {
    hQ[(size_t)t * 128 + r] = a1;
    hK[(size_t)t * 128 + r] = a2;
  } else {
    hV[(size_t)t * 128 + r] = a1;
  }
}

// dst[c][r] = (bf16)src[r][c]; src [R,C] fp32, dst [C,R] bf16; batched
__global__ __launch_bounds__(256) void transpose_to_bf16_kernel(
    const float* __restrict__ src, bf16_t* __restrict__ dst,
    int R, int C, size_t sbs, size_t dbs)
{
  __shared__ float tile[32][33];
  int b = blockIdx.z;
  int c0 = blockIdx.x * 32, r0 = blockIdx.y * 32;
  int tx = threadIdx.x & 31, ty = threadIdx.x >> 5;
  const float* s = src + (size_t)b * sbs;
  bf16_t* d = dst + (size_t)b * dbs;
#pragma unroll
  for (int i = 0; i < 4; i++)
    tile[ty + i * 8][tx] = s[(size_t)(r0 + ty + i * 8) * C + c0 + tx];
  __syncthreads();
#pragma unroll
  for (int i = 0; i < 4; i++)
    d[(size_t)(c0 + ty + i * 8) * R + r0 + tx] = (bf16_t)tile[tx][ty + i * 8];
}

// A_virt[t,k] = (bf16)(gb[t,k>>7]*h[t,k&127]), row-major [T,K]
__device__ __forceinline__ void avirt_body(
    const float* hr, const float* gr, bf16_t* ar, int K)
{
  int noct = K >> 3;
  for (int o = threadIdx.x; o < noct; o += 256) {
    int k = o * 8;
    float g = gr[k >> 7];
    bf16x8 v;
#pragma unroll
    for (int i = 0; i < 8; i++) v[i] = (bf16_t)(hr[(k & 127) + i] * g);
    *(bf16x8*)(ar + k) = v;
  }
}

__global__ __launch_bounds__(256) void avirt_kernel(
    const float* __restrict__ h, const float* __restrict__ gb, int NB,
    bf16_t* __restrict__ A, int K)
{
  int t = blockIdx.x;
  avirt_body(h + (size_t)t * 128, gb + (size_t)t * NB, A + (size_t)t * K, K);
}

__global__ __launch_bounds__(256) void avirt3_kernel(
    const float* __restrict__ h0, const float* __restrict__ h1,
    const float* __restrict__ h2, const float* __restrict__ g0,
    const float* __restrict__ g1, const float* __restrict__ g2, int NB,
    bf16_t* __restrict__ A0, bf16_t* __restrict__ A1,
    bf16_t* __restrict__ A2, int K)
{
  int t = blockIdx.x, y = blockIdx.y;
  const float* h = y == 0 ? h0 : y == 1 ? h1 : h2;
  const float* g = y == 0 ? g0 : y == 1 ? g1 : g2;
  bf16_t* A = y == 0 ? A0 : y == 1 ? A1 : A2;
  avirt_body(h + (size_t)t * 128, g + (size_t)t * NB, A + (size_t)t * K, K);
}

// out[i] += (float)p0[i] + (float)p1[i]  (bf16 partials, 8/thread)
__global__ __launch_bounds__(256) void combine2b_kernel(
    const bf16_t* __restrict__ p0, const bf16_t* __restrict__ p1,
    float* __restrict__ out)
{
  int i = (blockIdx.x * 256 + threadIdx.x) * 8;
  bf16x8 a = *(const bf16x8*)(p0 + i);
  bf16x8 b = *(const bf16x8*)(p1 + i);
  float4 o0 = ((float4*)(out + i))[0];
  float4 o1 = ((float4*)(out + i))[1];
  o0.x += (float)a[0] + (float)b[0];
  o0.y += (float)a[1] + (float)b[1];
  o0.z += (float)a[2] + (float)b[2];
  o0.w += (float)a[3] + (float)b[3];
  o1.x += (float)a[4] + (float)b[4];
  o1.y += (float)a[5] + (float)b[5];
  o1.z += (float)a[6] + (float)b[6];
  o1.w += (float)a[7] + (float)b[7];
  ((float4*)(out + i))[0] = o0;
  ((float4*)(out + i))[1] = o1;
}

// ======== epilogue helper (shared by all GEMM variants) ========
template <bool HAS_BIAS, bool HAS_RESID>
__device__ __forceinline__ void gemm_store(
    int mode, void* Cv, int ldc, const float* bias, const float* resid,
    int ldr, int rowb, int col, const f32x4& a)
{
  if (mode == 2) {
    bf16x4 v4;
#pragma unroll
    for (int r = 0; r < 4; r++) v4[r] = (bf16_t)a[r];
    bf16_t* dst = (bf16_t*)Cv +
        ((size_t)(rowb >> 10) * 1024 + col) * 1024 + (rowb & 1023);
    *(bf16x4*)dst = v4;
  } else {
#pragma unroll
    for (int r = 0; r < 4; r++) {
      int row = rowb + r;
      float v = a[r];
      if (HAS_BIAS) v += bias[col];
      if (HAS_RESID) v += resid[(size_t)row * ldr + col];
      if (mode == 1)
        ((bf16_t*)Cv)[(size_t)row * ldc + col] = (bf16_t)v;
      else
        ((float*)Cv)[(size_t)row * ldc + col] = v;
    }
  }
}

// ============== MFMA GEMM (64x128 tile) — narrow-N dispatches ==============
template <bool HAS_BIAS, bool HAS_RESID, int OUT_MODE>
__global__ __launch_bounds__(256) void mfma_gemm_kernel(
    const bf16_t* __restrict__ A, int lda,
    const bf16_t* __restrict__ Bt, int ldb,
    void* __restrict__ Cv, int ldc,
    const float* __restrict__ bias,
    const float* __restrict__ resid, int ldr,
    int M, int N, int K)
{
  __shared__ bf16_t As[2][64 * 32];
  __shared__ bf16_t Bs[2][128 * 32];
  int tid = threadIdx.x;
  int wave = tid >> 6, lane = tid & 63;

  unsigned lid = blockIdx.y * gridDim.x + blockIdx.x;
  unsigned nwg = gridDim.x * gridDim.y;
  unsigned swzb = lid;
  if ((nwg & 7u) == 0u) swzb = (lid & 7u) * (nwg >> 3) + (lid >> 3);
  int row0 = (int)(swzb / gridDim.x) * 64;
  int col0 = (int)(swzb % gridDim.x) * 128;

  int wr = (wave >> 1) * 32, wc = (wave & 1) * 64;
  f32x4 acc[2][4] = {};

  int srow = (wave << 4) + (lane >> 2);
  int g8 = (((lane & 3) ^ ((srow >> 1) & 3)) << 3);
  const bf16_t* gA = A + (size_t)(row0 + srow) * lda + g8;
  const bf16_t* gB = Bt + (size_t)(col0 + srow) * ldb + g8;
  size_t b64 = (size_t)64 * ldb;

  int fr = lane & 15, fq = lane >> 4;

#define GSTAGE(buf, k0s)                                  \
  {                                                       \
    GLDS16(gA + (k0s), &As[buf][wave * 512]);             \
    GLDS16(gB + (k0s), &Bs[buf][wave * 512]);             \
    GLDS16(gB + b64 + (k0s), &Bs[buf][2048 + wave * 512]);\
  }

  GSTAGE(0, 0);
  int cur = 0;
  for (int k0 = 0; k0 < K; k0 += 32) {
    __syncthreads();
    if (k0 + 32 < K) GSTAGE(cur ^ 1, k0 + 32);
    bf16x8 af[2], bfr[4];
#pragma unroll
    for (int m = 0; m < 2; m++) {
      int R = wr + m * 16 + fr;
      af[m] = *(const bf16x8*)&As[cur][R * 32 + ((fq ^ ((R >> 1) & 3)) << 3)];
    }
#pragma unroll
    for (int n = 0; n < 4; n++) {
      int R = wc + n * 16 + fr;
      bfr[n] = *(const bf16x8*)&Bs[cur][R * 32 + ((fq ^ ((R >> 1) & 3)) << 3)];
    }
#pragma unroll
    for (int m = 0; m < 2; m++)
#pragma unroll
      for (int n = 0; n < 4; n++)
        acc[m][n] = __builtin_amdgcn_mfma_f32_16x16x32_bf16(af[m], bfr[n],
                                                            acc[m][n], 0, 0, 0);
    cur ^= 1;
  }
#undef GSTAGE

#pragma unroll
  for (int m = 0; m < 2; m++)
#pragma unroll
    for (int n = 0; n < 4; n++)
      gemm_store<HAS_BIAS, HAS_RESID>(
          OUT_MODE, Cv, ldc, bias, resid, ldr,
          row0 + wr + m * 16 + fq * 4, col0 + wc + n * 16 + fr, acc[m][n]);
}

// ============== MFMA GEMM (128x128 tile) — wide dispatches ==============
// Per-z heterogeneous {A, lda, Bt, ldb, C, mode, K}.
struct ZArg { const bf16_t* A; int lda; const bf16_t* Bt; int ldb;
              void* C; int mode; int K; };

__device__ __forceinline__ void gemm128_body(
    const bf16_t* __restrict__ A, int lda, const bf16_t* __restrict__ Bt,
    int ldb, void* __restrict__ Cv, int ldc, int mode, int row0, int col0,
    int K)
{
  __shared__ bf16_t As[2][128 * 32];
  __shared__ bf16_t Bs[2][128 * 32];
  int tid = threadIdx.x;
  int wave = tid >> 6, lane = tid & 63;
  int wr = (wave >> 1) * 64, wc = (wave & 1) * 64;
  f32x4 acc[4][4] = {};

  int srow = (wave << 4) + (lane >> 2);
  int g8 = (((lane & 3) ^ ((srow >> 1) & 3)) << 3);
  const bf16_t* gA = A + (size_t)(row0 + srow) * lda + g8;
  const bf16_t* gB = Bt + (size_t)(col0 + srow) * ldb + g8;
  size_t a64 = (size_t)64 * lda, b64 = (size_t)64 * ldb;

  int fr = lane & 15, fq = lane >> 4;

#define GSTAGE8(buf, k0s)                                  \
  {                                                        \
    GLDS16(gA + (k0s), &As[buf][wave * 512]);              \
    GLDS16(gA + a64 + (k0s), &As[buf][2048 + wave * 512]); \
    GLDS16(gB + (k0s), &Bs[buf][wave * 512]);              \
    GLDS16(gB + b64 + (k0s), &Bs[buf][2048 + wave * 512]); \
  }

  GSTAGE8(0, 0);
  int cur = 0;
  for (int k0 = 0; k0 < K; k0 += 32) {
    __syncthreads();
    if (k0 + 32 < K) GSTAGE8(cur ^ 1, k0 + 32);
    bf16x8 af[4], bfr[4];
#pragma unroll
    for (int m = 0; m < 4; m++) {
      int R = wr + m * 16 + fr;
      af[m] = *(const bf16x8*)&As[cur][R * 32 + ((fq ^ ((R >> 1) & 3)) << 3)];
    }
#pragma unroll
    for (int n = 0; n < 4; n++) {
      int R = wc + n * 16 + fr;
      bfr[n] = *(const bf16x8*)&Bs[cur][R * 32 + ((fq ^ ((R >> 1) & 3)) << 3)];
    }
#pragma unroll
    for (int m = 0; m < 4; m++)
#pragma unroll
      for (int n = 0; n < 4; n++)
        acc[m][n] = __builtin_amdgcn_mfma_f32_16x16x32_bf16(af[m], bfr[n],
                                                            acc[m][n], 0, 0, 0);
    cur ^= 1;
  }
#undef GSTAGE8

#pragma unroll
  for (int m = 0; m < 4; m++)
#pragma unroll
    for (int n = 0; n < 4; n++)
      gemm_store<false, false>(
          mode, Cv, ldc, nullptr, nullptr, 0,
          row0 + wr + m * 16 + fq * 4, col0 + wc + n * 16 + fr, acc[m][n]);
}

__global__ __launch_bounds__(256) void mfma_gemm128b_kernel(
    ZArg za, ZArg zb, ZArg zc, int ldc)
{
  unsigned gx = gridDim.x;
  unsigned gxy = gridDim.x * gridDim.y;
  unsigned lid = (blockIdx.z * gridDim.y + blockIdx.y) * gx + blockIdx.x;
  unsigned nwg = gxy * gridDim.z;
  unsigned swzb = lid;
  if ((nwg & 7u) == 0u) swzb = (lid & 7u) * (nwg >> 3) + (lid >> 3);
  unsigned zi = swzb / gxy;
  unsigned rem = swzb % gxy;
  int row0 = (int)(rem / gx) * 128;
  int col0 = (int)(rem % gx) * 128;
  ZArg Z = (zi == 0) ? za : (zi == 1) ? zb : zc;
  gemm128_body(Z.A, Z.lda, Z.Bt, Z.ldb, Z.C, ldc, Z.mode, row0, col0, Z.K);
}

// ============== MFMA GEMM (256x128 tile, 8 waves) — big dispatches ==========
// 8 waves (4M x 2N), each wave 64x64 (acc[4][4]), same swizzle/staging idiom.
// Per K-step: A 256x32 + B 128x32 staged (3 GLDS16/thread), 128 wave-MFMAs.
__global__ __launch_bounds__(512) void mfma_gemm256b_kernel(
    ZArg za, ZArg zb, ZArg zc, int ldc)
{
  __shared__ bf16_t As[2][256 * 32];
  __shared__ bf16_t Bs[2][128 * 32];
  int tid = threadIdx.x;
  int wave = tid >> 6, lane = tid & 63;

  unsigned gx = gridDim.x;
  unsigned gxy = gridDim.x * gridDim.y;
  unsigned lid = (blockIdx.z * gridDim.y + blockIdx.y) * gx + blockIdx.x;
  unsigned nwg = gxy * gridDim.z;
  unsigned swzb = lid;
  if ((nwg & 7u) == 0u) swzb = (lid & 7u) * (nwg >> 3) + (lid >> 3);
  unsigned zi = swzb / gxy;
  unsigned rem = swzb % gxy;
  int row0 = (int)(rem / gx) * 256;
  int col0 = (int)(rem % gx) * 128;
  ZArg Z = (zi == 0) ? za : (zi == 1) ? zb : zc;

  int wr = (wave >> 1) * 64, wc = (wave & 1) * 64;
  f32x4 acc[4][4] = {};

  int srow = (wave << 4) + (lane >> 2);  // 0..127 across 8 waves
  int g8 = (((lane & 3) ^ ((srow >> 1) & 3)) << 3);
  const bf16_t* gA = Z.A + (size_t)(row0 + srow) * Z.lda + g8;
  const bf16_t* gB = Z.Bt + (size_t)(col0 + srow) * Z.ldb + g8;
  size_t a128 = (size_t)128 * Z.lda;
  int K = Z.K;

  int fr = lane & 15, fq = lane >> 4;

#define GSTAGE16(buf, k0s)                                  \
  {                                                         \
    GLDS16(gA + (k0s), &As[buf][wave * 512]);               \
    GLDS16(gA + a128 + (k0s), &As[buf][4096 + wave * 512]); \
    GLDS16(gB + (k0s), &Bs[buf][wave * 512]);               \
  }

  GSTAGE16(0, 0);
  int cur = 0;
  for (int k0 = 0; k0 < K; k0 += 32) {
    __syncthreads();
    if (k0 + 32 < K) GSTAGE16(cur ^ 1, k0 + 32);
    bf16x8 af[4], bfr[4];
#pragma unroll
    for (int m = 0; m < 4; m++) {
      int R = wr + m * 16 + fr;  // 0..255
      af[m] = *(const bf16x8*)&As[cur][R * 32 + ((fq ^ ((R >> 1) & 3)) << 3)];
    }
#pragma unroll
    for (int n = 0; n < 4; n++) {
      int R = wc + n * 16 + fr;  // 0..127
      bfr[n] = *(const bf16x8*)&Bs[cur][R * 32 + ((fq ^ ((R >> 1) & 3)) << 3)];
    }
#pragma unroll
    for (int m = 0; m < 4; m++)
#pragma unroll
      for (int n = 0; n < 4; n++)
        acc[m][n] = __builtin_amdgcn_mfma_f32_16x16x32_bf16(af[m], bfr[n],
                                                            acc[m][n], 0, 0, 0);
    cur ^= 1;
  }
#undef GSTAGE16

#pragma unroll
  for (int m = 0; m < 4; m++)
#pragma unroll
    for (int n = 0; n < 4; n++)
      gemm_store<false, false>(
          Z.mode, Z.C, ldc, nullptr, nullptr, 0,
          row0 + wr + m * 16 + fq * 4, col0 + wc + n * 16 + fr, acc[m][n]);
}

// ======================= MFMA flash attention (bf16, LDS-staged) ============
// 8 waves (512 thr), causal-pair balancing.
__global__ __launch_bounds__(512) void flash_mfma_kernel(
    const bf16_t* __restrict__ Q, const bf16_t* __restrict__ K,
    const bf16_t* __restrict__ Vt, bf16_t* __restrict__ O)
{
  __shared__ bf16_t Ks[2][64 * 64];
  __shared__ bf16_t Vs[2][64 * 64];
  __shared__ bf16_t Pl[8][32 * 64];

  int tid = threadIdx.x;
  int wave = tid >> 6, lane = tid & 63;
  int fr = lane & 15, fq = lane >> 4;
  unsigned lid = blockIdx.x + blockIdx.y * 4 + blockIdx.z * 64;  // 256 wgs
  unsigned swz8 = (lid & 7u) * 32 + (lid >> 3);
  int s_slot = swz8 & 3;
  unsigned hb = swz8 >> 2;
  int h = hb & 15, b = hb >> 4;
  int half = wave >> 2, w4 = wave & 3;
  int qb = half ? (7 - s_slot) : s_slot;
  int q0w = qb * 128 + w4 * 32;
  int KT = 16 - 2 * s_slot;
  size_t qkbase = ((size_t)b * 1024) * 1024 + (size_t)h * 64;
  size_t vtbase = ((size_t)b * 1024 + (size_t)h * 64) * 1024;

  int srow8 = lane >> 3;
  int scb = (((lane & 7) << 4) ^ (srow8 << 4)) >> 1;

#define FSTAGE(buf, kt)                                                     \
  {                                                                         \
    int k0s = (kt) * 64;                                                    \
    int row = wave * 8 + srow8;                                             \
    GLDS16(&K[qkbase + (size_t)(k0s + row) * 1024 + scb],                   \
           &Ks[buf][wave * 512]);                                           \
    GLDS16(&Vt[vtbase + (size_t)row * 1024 + k0s + scb],                    \
           &Vs[buf][wave * 512]);                                           \
  }

  bf16x8 qf[2][2];
#pragma unroll
  for (int g = 0; g < 2; g++)
#pragma unroll
    for (int kh = 0; kh < 2; kh++)
      qf[g][kh] = *(const bf16x8*)&Q[qkbase +
                                     (size_t)(q0w + g * 16 + fr) * 1024 +
                                     kh * 32 + fq * 8];

  f32x4 o_acc[2][4] = {};
  float mrow[2][4], lrow[2][4];
#pragma unroll
  for (int g = 0; g < 2; g++)
#pragma unroll
    for (int r = 0; r < 4; r++) { mrow[g][r] = -INFINITY; lrow[g][r] = 0.f; }

  char* P = (char*)&Pl[wave][0];

  FSTAGE(0, 0);

  for (int kt = 0; kt < KT; kt++) {
    __syncthreads();
    if (kt + 1 < KT) FSTAGE((kt + 1) & 1, kt + 1);
    int k0 = kt * 64;
    if (k0 <= q0w + 31) {
      const char* Kb = (const char*)&Ks[kt & 1][0];
      const char* Vb = (const char*)&Vs[kt & 1][0];
      int swz = (fr & 7) << 4;
      f32x4 s[2][4] = {};
#pragma unroll
      for (int n = 0; n < 4; n++) {
        int rowo = (n * 16 + fr) * 128;
        bf16x8 kf0 = *(const bf16x8*)(Kb + rowo + ((fq * 16) ^ swz));
        bf16x8 kf1 = *(const bf16x8*)(Kb + rowo + ((64 + fq * 16) ^ swz));
#pragma unroll
        for (int g = 0; g < 2; g++) {
          s[g][n] = __builtin_amdgcn_mfma_f32_16x16x32_bf16(qf[g][0], kf0,
                                                            s[g][n], 0, 0, 0);
          s[g][n] = __builtin_amdgcn_mfma_f32_16x16x32_bf16(qf[g][1], kf1,
                                                            s[g][n], 0, 0, 0);
        }
      }
      const float scale = 0.125f;
#pragma unroll
      for (int g = 0; g < 2; g++) {
        bool dm = (k0 + 63 > q0w + g * 16);
#pragma unroll
        for (int n = 0; n < 4; n++)
#pragma unroll
          for (int r = 0; r < 4; r++) {
            float v = s[g][n][r] * scale;
            if (dm && (k0 + n * 16 + fr > q0w + g * 16 + fq * 4 + r))
              v = -INFINITY;
            s[g][n][r] = v;
          }
      }
      float corr[2][4];
#pragma unroll
      for (int g = 0; g < 2; g++)
#pragma unroll
        for (int r = 0; r < 4; r++) {
          float mx = fmaxf(fmaxf(s[g][0][r], s[g][1][r]),
                           fmaxf(s[g][2][r], s[g][3][r]));
#pragma unroll
          for (int msk = 1; msk < 16; msk <<= 1)
            mx = fmaxf(mx, __shfl_xor(mx, msk));
          float mnew = fmaxf(mrow[g][r], mx);
          corr[g][r] = __expf(mrow[g][r] - mnew);
          mrow[g][r] = mnew;
          float ps = 0.f;
#pragma unroll
          for (int n = 0; n < 4; n++) {
            float p = __expf(s[g][n][r] - mnew);
            s[g][n][r] = p;
            ps += p;
          }
#pragma unroll
          for (int msk = 1; msk < 16; msk <<= 1) ps += __shfl_xor(ps, msk);
          lrow[g][r] = lrow[g][r] * corr[g][r] + ps;
        }
#pragma unroll
      for (int g = 0; g < 2; g++)
#pragma unroll
        for (int n = 0; n < 4; n++)
#pragma unroll
          for (int r = 0; r < 4; r++) {
            int q = g * 16 + fq * 4 + r;
            int cb = ((n * 16 + fr) * 2) ^ ((q & 7) << 4);
            *(bf16_t*)(P + q * 128 + cb) = (bf16_t)s[g][n][r];
          }
      int rr = fr & 3;
      int srcl = (fr >> 2) << 4;
#pragma unroll
      for (int g = 0; g < 2; g++) {
        float c0 = __shfl(corr[g][0], srcl);
        float c1 = __shfl(corr[g][1], srcl);
        float c2 = __shfl(corr[g][2], srcl);
        float c3 = __shfl(corr[g][3], srcl);
        float cq = rr == 0 ? c0 : rr == 1 ? c1 : rr == 2 ? c2 : c3;
#pragma unroll
        for (int n = 0; n < 4; n++)
#pragma unroll
          for (int r = 0; r < 4; r++) o_acc[g][n][r] *= cq;
      }
#pragma unroll
      for (int c = 0; c < 2; c++) {
        bf16x8 pf[2];
#pragma unroll
        for (int g = 0; g < 2; g++)
          pf[g] = *(const bf16x8*)(P + (g * 16 + fr) * 128 +
                                   ((c * 64 + fq * 16) ^ swz));
#pragma unroll
        for (int n = 0; n < 4; n++) {
          bf16x8 vf = *(const bf16x8*)(Vb + (n * 16 + fr) * 128 +
                                       ((c * 64 + fq * 16) ^ swz));
#pragma unroll
          for (int g = 0; g < 2; g++)
            o_acc[g][n] = __builtin_amdgcn_mfma_f32_16x16x32_bf16(
                vf, pf[g], o_acc[g][n], 0, 0, 0);
        }
      }
    }
  }
  int rr = fr & 3;
  int srcl = (fr >> 2) << 4;
#pragma unroll
  for (int g = 0; g < 2; g++) {
    float l0 = __shfl(lrow[g][0], srcl);
    float l1 = __shfl(lrow[g][1], srcl);
    float l2 = __shfl(lrow[g][2], srcl);
    float l3 = __shfl(lrow[g][3], srcl);
    float lq = rr == 0 ? l0 : rr == 1 ? l1 : rr == 2 ? l2 : l3;
    float linv = 1.f / lq;
    size_t orow = qkbase + (size_t)(q0w + g * 16 + fr) * 1024;
#pragma unroll
    for (int n = 0; n < 4; n++) {
      bf16x4 ov;
#pragma unroll
      for (int r = 0; r < 4; r++) ov[r] = (bf16_t)(o_acc[g][n][r] * linv);
      *(bf16x4*)&O[orow + n * 16 + fq * 4] = ov;
    }
  }
#undef FSTAGE
}

// ======================= launch =======================

extern "C" void kernel_launch(void* const* d_in, const int* in_sizes, int n_in,
                              void* d_out, int out_size, void* d_ws,
                              size_t ws_size, hipStream_t stream) {
  (void)in_sizes; (void)n_in; (void)out_size; (void)ws_size;
  const float* x          = (const float*)d_in[0];
  const float* qk_emb     = (const float*)d_in[1];
  const float* v_emb      = (const float*)d_in[2];
  const float* know_emb   = (const float*)d_in[3];
  const float* qk_f       = (const float*)d_in[4];
  const float* qk_r       = (const float*)d_in[5];
  const float* v_f        = (const float*)d_in[6];
  const float* v_r        = (const float*)d_in[7];
  const float* know_f     = (const float*)d_in[8];
  const float* know_r     = (const float*)d_in[9];
  const float* proj_attn_k = (const float*)d_in[10];
  const float* proj_attn_b = (const float*)d_in[11];
  const float* tau_attn_k  = (const float*)d_in[12];
  const float* tau_attn_b  = (const float*)d_in[13];
  const float* proj_know_k = (const float*)d_in[14];
  const float* proj_know_b = (const float*)d_in[15];
  const float* tau_know_k  = (const float*)d_in[16];
  const float* tau_know_b  = (const float*)d_in[17];
  const float* expand_O    = (const float*)d_in[18];
  const float* ln1_scale   = (const float*)d_in[19];
  const float* ln1_bias    = (const float*)d_in[20];
  const float* ln2_scale   = (const float*)d_in[21];
  const float* ln2_bias    = (const float*)d_in[22];

  float* out = (float*)d_out;  // [T,D] + aux scalar
  float* aux = out + (size_t)T * D;

  // ---- workspace arena ----
  float* ws = (float*)d_ws;
  float* n_f   = ws;                       // 4M floats
  float* tau3  = n_f + 4194304;            // 16K
  float* gq_b  = tau3 + 16384;             // 64K
  float* gk_b  = gq_b + 65536;
  float* gv_b  = gk_b + 65536;
  float* gkn_b = gv_b + 65536;             // 128K
  float* csum  = gkn_b + 131072;           // 8192
  float* rinv  = csum + 8192;              // 4*T
  float* hQ    = rinv + 16384;             // 512K
  float* hK    = hQ + 524288;
  float* hV    = hK + 524288;
  float* qkvarena = hV + 524288;           // 12.58M floats
  float* buf_big = qkvarena + 12582912;    // 16.78M floats (67MB)

  bf16_t* Qbb = (bf16_t*)qkvarena;                 // T*1024 bf16
  bf16_t* Kbb = Qbb + (size_t)T * 1024;
  bf16_t* Vtb = Kbb + (size_t)T * 1024;            // [4][1024][1024]

  bf16_t* nb   = (bf16_t*)(buf_big + 16777216);  // T*1024
  bf16_t* hab  = nb + 4194304;                   // T*384 (know: T*128)
  bf16_t* embB = hab + 1572864;                  // 524288
  bf16_t* B2t  = embB + 524288;                  // 4096*1024
  bf16_t* wt   = B2t + 4194304;
  bf16_t* pa_t  = wt;                   // 384*1024
  bf16_t* qkr_t = pa_t + 393216;        // 1024*2048
  bf16_t* vr_t  = qkr_t + 2097152;      // 1024*2048
  bf16_t* knr_t = vr_t + 2097152;       // 1024*4096
  bf16_t* eo_t  = knr_t + 4194304;      // 1024*1024
  bf16_t* pk_t  = eo_t + 1048576;       // 128*1024
  bf16_t* B2t2  = pk_t + 131072;        // 4096*1024

  // buf_big overlays (lifetimes checked):
  bf16_t* s_qb = (bf16_t*)buf_big;                  // [T,2048] bf16 16MB
  bf16_t* s_kb = s_qb + (size_t)T * 2048;           // 16..32MB
  bf16_t* s_vb = s_kb + (size_t)T * 2048;           // 32..48MB
  bf16_t* kscb = (bf16_t*)buf_big;                  // know scores [T,4096]
  bf16_t* allh_q = (bf16_t*)buf_big;                // T*2048 bf16
  bf16_t* allh_v = allh_q + (size_t)T * 2048;
  bf16_t* avbQ = (bf16_t*)buf_big;
  bf16_t* avbK = avbQ + (size_t)T * 2048;
  bf16_t* avbV = avbK + (size_t)T * 2048;
  bf16_t* avbN = (bf16_t*)buf_big;                  // know [T,4096] bf16
  bf16_t* allh_n = (bf16_t*)buf_big;                // aliases kscb (seq.)
  bf16_t* kp0 = (bf16_t*)(buf_big + 8388608);       // bf16 partial 32..40MB
  bf16_t* kp1 = kp0 + 4194304;                      // 40..48MB
  bf16_t* attnb_b = (bf16_t*)(buf_big + 12582912);  // T*1024 bf16

  bf16_t* embQ = embB;
  bf16_t* embV = embB + 262144;

  dim3 blk(256);

  zero1_kernel<<<1, 1, 0, stream>>>(aux);

  // weight + feature-basis transposes to bf16 [N,K]
  transpose_to_bf16_kernel<<<dim3(12, 32, 1), blk, 0, stream>>>(
      proj_attn_k, pa_t, 1024, 384, 0, 0);
  transpose_to_bf16_kernel<<<dim3(32, 64, 1), blk, 0, stream>>>(
      qk_r, qkr_t, 2048, 1024, 0, 0);
  transpose_to_bf16_kernel<<<dim3(32, 64, 1), blk, 0, stream>>>(
      v_r, vr_t, 2048, 1024, 0, 0);
  transpose_to_bf16_kernel<<<dim3(32, 128, 1), blk, 0, stream>>>(
      know_r, knr_t, 4096, 1024, 0, 0);
  transpose_to_bf16_kernel<<<dim3(32, 32, 1), blk, 0, stream>>>(
      expand_O, eo_t, 1024, 1024, 0, 0);
  transpose_to_bf16_kernel<<<dim3(4, 32, 1), blk, 0, stream>>>(
      proj_know_k, pk_t, 1024, 128, 0, 0);
  transpose_to_bf16_kernel<<<dim3(4, 32, 16), blk, 0, stream>>>(
      qk_f, B2t, 1024, 128, 131072, 131072);
  transpose_to_bf16_kernel<<<dim3(4, 32, 16), blk, 0, stream>>>(
      v_f, B2t2, 1024, 128, 131072, 131072);

  // ---- attention circuit ----
  ln_kernel<<<T, blk, 0, stream>>>(x, ln1_scale, ln1_bias, n_f, nb);
  norm_rows2_kernel<<<4096, 64, 0, stream>>>(qk_emb, embQ, v_emb, embV, 2048);

  mfma_gemm_kernel<true, false, 1><<<dim3(3, 64), blk, 0, stream>>>(
      nb, 1024, pa_t, 1024, hab, 384, proj_attn_b, nullptr, 0, T, 384, 1024);
  tau_kernel<<<T, 64, 0, stream>>>(n_f, tau_attn_k, tau_attn_b, tau3, 3);

  // batched gate-score GEMMs (z = {q,k,v}, K=128) -> bf16 scores
  {
    ZArg zq{hab + 0, 384, embQ, 128, s_qb, 1, 128};
    ZArg zk{hab + 128, 384, embQ, 128, s_kb, 1, 128};
    ZArg zv{hab + 256, 384, embV, 128, s_vb, 1, 128};
    mfma_gemm128b_kernel<<<dim3(16, 32, 3), blk, 0, stream>>>(
        zq, zk, zv, 2048);
  }
  gate3b_kernel<8><<<dim3(T, 3), blk, 0, stream>>>(
      s_qb, s_kb, s_vb, tau3, gq_b, gk_b, gv_b, rinv, 2048, 16);
  hipMemsetAsync(csum, 0, 6144 * sizeof(float), stream);
  colsumb_part3_kernel<<<dim3(8, 32, 3), blk, 0, stream>>>(
      s_qb, s_kb, s_vb, tau3, rinv, 2048, csum);
  colsum_fin_kernel<<<24, blk, 0, stream>>>(csum, 2048, 1.f / 2048.f, aux);

  // batched feature GEMMs (z = {qk,v}, K=1024), 256x128 tile -> bf16 all_h
  {
    ZArg zf1{nb, 1024, B2t, 1024, allh_q, 1, 1024};
    ZArg zf2{nb, 1024, B2t2, 1024, allh_v, 1, 1024};
    mfma_gemm256b_kernel<<<dim3(16, 16, 2), dim3(512), 0, stream>>>(
        zf1, zf2, zf1, 2048);
  }
  // know_f transpose: B2t free now; fills gap before knowledge circuit
  transpose_to_bf16_kernel<<<dim3(4, 32, 32), blk, 0, stream>>>(
      know_f, B2t, 1024, 128, 131072, 131072);
  wsum2b_kernel<<<dim3(T, 2), 128, 0, stream>>>(allh_q, allh_v, gq_b, gk_b,
                                                gv_b, hQ, hK, hV, 16);

  // batched avirt + batched QKV restore (256x128 tile)
  avirt3_kernel<<<dim3(T, 3), blk, 0, stream>>>(hQ, hK, hV, gq_b, gk_b, gv_b,
                                                16, avbQ, avbK, avbV, 2048);
  {
    ZArg zq{avbQ, 2048, qkr_t, 2048, Qbb, 1, 2048};
    ZArg zk{avbK, 2048, qkr_t, 2048, Kbb, 1, 2048};
    ZArg zv{avbV, 2048, vr_t, 2048, Vtb, 2, 2048};
    mfma_gemm256b_kernel<<<dim3(8, 16, 3), dim3(512), 0, stream>>>(
        zq, zk, zv, 1024);
  }

  // MFMA flash attention (causal-paired, 512 thr) + output proj + residual
  flash_mfma_kernel<<<dim3(4, 16, 4), dim3(512), 0, stream>>>(Qbb, Kbb, Vtb,
                                                              attnb_b);
  mfma_gemm_kernel<false, true, 0><<<dim3(8, 64), blk, 0, stream>>>(
      attnb_b, 1024, eo_t, 1024, out, 1024, nullptr, x, 1024, T, 1024, 1024);

  // ---- knowledge circuit ----
  ln_kernel<<<T, blk, 0, stream>>>(out, ln2_scale, ln2_bias, n_f, nb);
  norm_rows_kernel<<<4096, 64, 0, stream>>>(know_emb, embB);
  mfma_gemm_kernel<true, false, 1><<<dim3(1, 64), blk, 0, stream>>>(
      nb, 1024, pk_t, 1024, hab, 128, proj_know_b, nullptr, 0, T, 128, 1024);
  tau_kernel<<<T, 64, 0, stream>>>(n_f, tau_know_k, tau_know_b, tau3, 1);

  // know scores -> bf16 (kscb in buf_big[0..32MB])
  {
    ZArg zs{hab, 128, embB, 128, kscb, 1, 128};
    mfma_gemm128b_kernel<<<dim3(32, 32, 1), blk, 0, stream>>>(
        zs, zs, zs, 4096);
  }
  gateb_kernel<16><<<T, blk, 0, stream>>>(kscb, tau3, gkn_b, rinv + 3 * T,
                                          4096, 32);
  hipMemsetAsync(csum, 0, 4096 * sizeof(float), stream);
  colsumb_part_kernel<<<dim3(16, 32), blk, 0, stream>>>(
      kscb, tau3, rinv + 3 * T, 4096, csum);
  colsum_fin_kernel<<<16, blk, 0, stream>>>(csum, 4096, 1.f / 4096.f, aux);

  // know features -> bf16 (allh_n aliases kscb; kscb dead), 256x128 tile
  {
    ZArg zf{nb, 1024, B2t, 1024, allh_n, 1, 1024};
    mfma_gemm256b_kernel<<<dim3(32, 16, 1), dim3(512), 0, stream>>>(
        zf, zf, zf, 4096);
  }
  wsum2_kernel<<<T, 128, 0, stream>>>(allh_n, gkn_b, nullptr, hQ, nullptr, 32);

  // knowledge restore: split-K=2 -> bf16 partials + combine (256x128 tile)
  avirt_kernel<<<T, blk, 0, stream>>>(hQ, gkn_b, 32, avbN, 4096);
  {
    ZArg z0{avbN, 4096, knr_t, 4096, kp0, 1, 2048};
    ZArg z1{avbN + 2048, 4096, knr_t + 2048, 4096, kp1, 1, 2048};
    mfma_gemm256b_kernel<<<dim3(8, 16, 2), dim3(512), 0, stream>>>(
        z0, z1, z0, 1024);
  }
  combine2b_kernel<<<2048, blk, 0, stream>>>(kp0, kp1, out);
}